// Round 14
// baseline (302.986 us; speedup 1.0000x reference)
//
#include <hip/hip_runtime.h>

typedef unsigned short u16;
typedef __attribute__((ext_vector_type(4))) u16 u16x4;
typedef __attribute__((ext_vector_type(8))) u16 u16x8;
typedef __attribute__((ext_vector_type(8))) short s16x8;   // 8 x bf16 (4 VGPRs)
typedef __attribute__((ext_vector_type(4))) float f32x4;
typedef __attribute__((ext_vector_type(16))) float f32x16;
typedef __attribute__((ext_vector_type(4))) unsigned u32x4;

#define B_  4
#define C_  512
#define CI_ 256
#define HW_ 4096

static __device__ __forceinline__ u16 f2bf(float f) {
  unsigned u = __float_as_uint(f);
  return (u16)((u + 0x7FFFu + ((u >> 16) & 1u)) >> 16);   // RNE
}
static __device__ __forceinline__ float bf2f(u16 h) {
  return __uint_as_float(((unsigned)h) << 16);
}

static __device__ __forceinline__ f32x4 mfma16(s16x8 a, s16x8 b, f32x4 c) {
  return __builtin_amdgcn_mfma_f32_16x16x32_bf16(a, b, c, 0, 0, 0);
}
static __device__ __forceinline__ f32x16 mfma32(s16x8 a, s16x8 b, f32x16 c) {
  return __builtin_amdgcn_mfma_f32_32x32x16_bf16(a, b, c, 0, 0, 0);
}

typedef __attribute__((address_space(3))) unsigned int as3_u32;
typedef const __attribute__((address_space(1))) unsigned int as1_u32;
static __device__ __forceinline__ void gload16(const u16* g, u16* l) {
  __builtin_amdgcn_global_load_lds((as1_u32*)g, (as3_u32*)l, 16, 0, 0);
}

// ---------------------------------------------------------------------------
// K0w: convert weights to bf16.  wB[768][512] = {g_w, theta_w, phi_w};
//      WwB[512][256] = W_w.
// ---------------------------------------------------------------------------
__global__ __launch_bounds__(256) void k0_wcvt(
    const float* __restrict__ wg, const float* __restrict__ wt,
    const float* __restrict__ wp, const float* __restrict__ Ww,
    u16* __restrict__ wB, u16* __restrict__ WwB)
{
  int idx = (blockIdx.x * 256 + threadIdx.x) * 8;   // over 524288 elems
  const float* src;
  u16* dst;
  if (idx < 393216) {
    int r = idx >> 17;                 // 0..2 region of 131072
    src = (r == 0 ? wg : r == 1 ? wt : wp) + (idx & 131071);
    dst = wB + idx;
  } else {
    src = Ww + (idx - 393216);
    dst = WwB + (idx - 393216);
  }
  float4 v0 = *reinterpret_cast<const float4*>(src);
  float4 v1 = *reinterpret_cast<const float4*>(src + 4);
  u16x8 h;
  h[0] = f2bf(v0.x); h[1] = f2bf(v0.y); h[2] = f2bf(v0.z); h[3] = f2bf(v0.w);
  h[4] = f2bf(v1.x); h[5] = f2bf(v1.y); h[6] = f2bf(v1.z); h[7] = f2bf(v1.w);
  *reinterpret_cast<u16x8*>(dst) = h;
}

// ---------------------------------------------------------------------------
// K0x: x (b0+z) (C,HW) f32 -> xT (z,HW,C) bf16 token-major; 64x64 LDS tiles.
// ---------------------------------------------------------------------------
__global__ __launch_bounds__(256) void k0_xt(
    const float* __restrict__ x, u16* __restrict__ xT, int b0)
{
  __shared__ u16 lds[64][72];   // [c][n]
  const int tid = threadIdx.x;
  const int n0 = blockIdx.x * 64, c0 = blockIdx.y * 64;
  const int bl = blockIdx.z;            // 0..1 local
  const int b = b0 + bl;
  const int nc = (tid & 15) * 4;
#pragma unroll
  for (int i = 0; i < 4; ++i) {
    int cr = (tid >> 4) + i * 16;
    float4 v = *reinterpret_cast<const float4*>(
        &x[((size_t)(b * C_ + c0 + cr)) * HW_ + n0 + nc]);
    u16x4 h; h[0] = f2bf(v.x); h[1] = f2bf(v.y); h[2] = f2bf(v.z); h[3] = f2bf(v.w);
    *reinterpret_cast<u16x4*>(&lds[cr][nc]) = h;
  }
  __syncthreads();
  const int n = tid & 63, cg = tid >> 6;
  u16x8 o0, o1;
#pragma unroll
  for (int j = 0; j < 8; ++j) { o0[j] = lds[cg * 16 + j][n]; o1[j] = lds[cg * 16 + 8 + j][n]; }
  size_t dstb = ((size_t)bl * HW_ + n0 + n) * C_ + c0 + cg * 16;
  *reinterpret_cast<u16x8*>(&xT[dstb])     = o0;
  *reinterpret_cast<u16x8*>(&xT[dstb + 8]) = o1;
}

// ---------------------------------------------------------------------------
// K1: fused projections as one staged NT GEMM (per 2-batch half).
//   tile 128x128, BK=32, triple-buffered counted-vmcnt staging.  (R5-proven)
// ---------------------------------------------------------------------------
__global__ __launch_bounds__(256) void k1_proj(
    const u16* __restrict__ wB, const u16* __restrict__ xT,
    const float* __restrict__ bg, const float* __restrict__ bt, const float* __restrict__ bp,
    u16* __restrict__ g_s, u16* __restrict__ thetaT, u16* __restrict__ phiT, int half)
{
  extern __shared__ u16 sm1[];   // 3 bufs of 8192 u16: A@+0 (4096), B@+4096
  const int tid = threadIdx.x;
  const int lane = tid & 63, wid = tid >> 6;
  const int wm = wid >> 1, wn = wid & 1;
  const int l15 = lane & 15, g4 = lane >> 4;

  const int bid = blockIdx.x;            // 384 = 12 * 32
  const int r12 = bid % 12;
  const int nt = bid / 12;               // 0..31
  const int mt = r12 >> 1;               // 0..5 (p = mt>>1)
  const int bl = r12 & 1;                // local batch
  const int b = half * 2 + bl;
  const int m0 = mt * 128, n0g = nt * 128;
  const int p = mt >> 1;

  const u16* xb = xT + (size_t)bl * HW_ * C_;

  const int srow = tid >> 2, sch = tid & 3;
  const u16* a_src = wB + (size_t)(m0 + srow) * C_ + sch * 8;
  const u16* b_src = xb + (size_t)(n0g + srow) * C_ + sch * 8;

  f32x4 acc[4][4] = {};

  auto stage1 = [&](int buf, int ks) {
    u16* d = sm1 + buf * 8192;
#pragma unroll
    for (int i = 0; i < 2; ++i) {
      gload16(a_src + (size_t)(i * 64) * C_ + ks * 32, d + (tid + i * 256) * 8);
      gload16(b_src + (size_t)(i * 64) * C_ + ks * 32, d + 4096 + (tid + i * 256) * 8);
    }
  };
  auto compute1 = [&](int buf) {
    const u16* A = sm1 + buf * 8192;
    const u16* Bt = A + 4096;
    s16x8 afr[4], bfr[4];
#pragma unroll
    for (int mf = 0; mf < 4; ++mf)
      afr[mf] = *reinterpret_cast<const s16x8*>(&A[(wm * 64 + mf * 16 + l15) * 32 + g4 * 8]);
#pragma unroll
    for (int nf = 0; nf < 4; ++nf)
      bfr[nf] = *reinterpret_cast<const s16x8*>(&Bt[(wn * 64 + nf * 16 + l15) * 32 + g4 * 8]);
#pragma unroll
    for (int mf = 0; mf < 4; ++mf)
#pragma unroll
      for (int nf = 0; nf < 4; ++nf)
        acc[mf][nf] = mfma16(afr[mf], bfr[nf], acc[mf][nf]);
  };

  stage1(0, 0); stage1(1, 1);
  int cur = 0;
#pragma unroll 1
  for (int ks = 0; ks < 15; ++ks) {
    asm volatile("s_waitcnt vmcnt(4)" ::: "memory");
    __builtin_amdgcn_s_barrier();
    compute1(cur);
    if (ks < 14) { int nb = cur + 2; if (nb >= 3) nb -= 3; stage1(nb, ks + 2); }
    cur = (cur == 2) ? 0 : cur + 1;
  }
  asm volatile("s_waitcnt vmcnt(0)" ::: "memory");
  __builtin_amdgcn_s_barrier();
  compute1(cur);          // ks = 15
  __syncthreads();        // all waves done reading bufs before lds_t overlay

  const float* bias = (p == 0) ? bg : (p == 1) ? bt : bp;
  const int cib = (mt & 1) * 128;
#pragma unroll
  for (int mf = 0; mf < 4; ++mf)
#pragma unroll
    for (int r = 0; r < 4; ++r) {
      float bv = bias[cib + wm * 64 + mf * 16 + g4 * 4 + r];
#pragma unroll
      for (int nf = 0; nf < 4; ++nf) acc[mf][nf][r] += bv;
    }

  if (p == 0) {
    // g: channel-major store via LDS transpose.  lds_t [128][136] u16
    u16* lds_t = sm1;
#pragma unroll
    for (int mf = 0; mf < 4; ++mf)
#pragma unroll
      for (int nf = 0; nf < 4; ++nf)
#pragma unroll
        for (int r = 0; r < 4; ++r)
          lds_t[(wm * 64 + mf * 16 + g4 * 4 + r) * 136 + wn * 64 + nf * 16 + l15] =
              f2bf(acc[mf][nf][r]);
    __syncthreads();
    const int m = tid >> 1, hh = tid & 1;
    size_t dst = ((size_t)b * CI_ + cib + m) * HW_ + n0g + hh * 64;
#pragma unroll
    for (int j = 0; j < 8; ++j)
      *reinterpret_cast<u16x8*>(&g_s[dst + j * 8]) =
          *reinterpret_cast<const u16x8*>(&lds_t[m * 136 + hh * 64 + j * 8]);
  } else {
    u16* outp = (p == 1) ? thetaT : phiT;
#pragma unroll
    for (int mf = 0; mf < 4; ++mf)
#pragma unroll
      for (int nf = 0; nf < 4; ++nf) {
        u16x4 h;
#pragma unroll
        for (int r = 0; r < 4; ++r) h[r] = f2bf(acc[mf][nf][r]);
        int n = n0g + wn * 64 + nf * 16 + l15;
        *reinterpret_cast<u16x4*>(
            &outp[((size_t)b * HW_ + n) * CI_ + cib + wm * 64 + mf * 16 + g4 * 4]) = h;
      }
  }
}

// ---------------------------------------------------------------------------
// K3: fused attention, 32x32 MFMA, P in registers — 4-wave (256-thr) blocks.
//  The R12/R13 8-wave version hit the 2-waves/SIMD 256-reg hard cap and
//  spilled oacc.  A 4-wave block runs 1 wave/SIMD -> 512-reg cap: the full
//  footprint (oacc[8]=128 AGPR + thfr[16]=64 + temps) fits with no scratch.
//  n-tile 32, m-tile 128, 32 iters, 512 blocks (2 sequential rounds/CU).
//  Wave w owns m-slice w*32: QK (PHI swizzled LDS x theta regs) -> exp/pack
//  -> shfl_xor h-half handoff (R12-verified) -> PV into oacc[8] (all 256 c).
//  LDS: PHI [128][256] 64KB + G [256][128] 64KB + L = 131712 B.
//  Conservative 2-sync skeleton:
//    A_it: { stage_g(it); qk(it) }   sync
//    B_it: { stage_phi(it+1); pv(it) } sync
// ---------------------------------------------------------------------------
#define OFF_PHI  0        // [128][256] u16 (65536 B)
#define OFF_G    32768    // [256][128] u16 (65536 B)
#define OFF_LPW  65536    // u16 index; f32 Lp[4][32]+iL[32] -> total 131712 B

__global__ __launch_bounds__(256, 1) void k3_fused(
    const u16* __restrict__ thetaT, const u16* __restrict__ phiT,
    const u16* __restrict__ g_s, u16* __restrict__ y)
{
  extern __shared__ u16 smem[];
  float* Lp = (float*)(smem + OFF_LPW);  // [4][32]
  float* iL = Lp + 128;                  // [32]

  const int tid = threadIdx.x;
  const int lane = tid & 63, w = tid >> 6;   // w in 0..3
  const int l31 = lane & 31, h = lane >> 5;  // h in 0..1
  const int l15 = lane & 15;

  const int bid = blockIdx.x;            // 512 = 8 xcd * 64
  const int xcd = bid & 7, slot = bid >> 3;
  const int b  = xcd >> 1;
  const int n0 = ((xcd & 1) * 64 + slot) * 32;   // 128 n-tiles of 32 per batch

  const u16* thb = thetaT + (size_t)b * HW_ * CI_;
  const u16* phb = phiT   + (size_t)b * HW_ * CI_;
  const u16* gsb = g_s    + (size_t)b * CI_ * HW_;

  // theta hoist: the block's 32 n-rows, k = cs*16 + h*8 + e  (64 VGPR).
  // All 4 waves load the same tile (L2-served, once per block).
  s16x8 thfr[16];
#pragma unroll
  for (int cs = 0; cs < 16; ++cs)
    thfr[cs] = *reinterpret_cast<const s16x8*>(
        &thb[(size_t)(n0 + l31) * CI_ + cs * 16 + h * 8]);

  // staging maps (pre-swizzled global source, linear LDS dest = tid*16B).
  // PHI: 8 rows/issue, 16 issues; row&15 alternates prow / prow^8 with i&1.
  const int prow = tid >> 5, pj = tid & 31;   // prow 0..7
  const int grow = tid >> 4, gj = tid & 15;   // grow 0..15
  const u16* ph_srcE = phb + (size_t)prow * CI_ + ((pj ^ prow) * 8);
  const u16* ph_srcO = phb + (size_t)prow * CI_ + ((pj ^ prow ^ 8) * 8);
  const u16* g_src   = gsb + (size_t)grow * HW_ + ((gj ^ grow) * 8);
  const int ph_do = prow * 256 + pj * 8;
  const int g_do  = grow * 128 + gj * 8;

  auto stage_phi = [&](int mt) {
#pragma unroll
    for (int i = 0; i < 16; ++i) {
      const u16* s = (i & 1) ? ph_srcO : ph_srcE;
      gload16(s + (size_t)(mt + i * 8) * CI_, smem + OFF_PHI + ph_do + i * 2048);
    }
  };
  auto stage_g = [&](int mt) {
#pragma unroll
    for (int i = 0; i < 16; ++i)
      gload16(g_src + mt + (size_t)(i * 16) * HW_, smem + OFF_G + g_do + i * 2048);
  };

  f32x16 oacc[8] = {};
  float psum = 0.f;
  s16x8 pa0, pa1;

  auto qk_it = [&]() {
    const u16* phc = smem + OFF_PHI;
    f32x16 acc = {};
    __builtin_amdgcn_s_setprio(1);
#pragma unroll
    for (int cs = 0; cs < 16; ++cs) {
      s16x8 a = *reinterpret_cast<const s16x8*>(
          &phc[(w * 32 + l31) * 256 + (((cs * 2 + h) ^ l15) * 8)]);
      acc = mfma32(a, thfr[cs], acc);
    }
    __builtin_amdgcn_s_setprio(0);
    // lane (l31=n, h) holds P[m][n], m(local) = (reg&3) + 8*(reg>>2) + 4*h
    float p[16];
#pragma unroll
    for (int r = 0; r < 16; ++r) {
      p[r] = __expf(acc[r] * 0.0625f);
      psum += p[r];
    }
    // pack q-groups: q[qi] covers m = 8*qi + 4*h + {0..3}
    unsigned q[4][2];
#pragma unroll
    for (int qi = 0; qi < 4; ++qi) {
      q[qi][0] = ((unsigned)f2bf(p[4 * qi + 1]) << 16) | f2bf(p[4 * qi]);
      q[qi][1] = ((unsigned)f2bf(p[4 * qi + 3]) << 16) | f2bf(p[4 * qi + 2]);
    }
    // h-half exchange (lane ^ 32): h=0 sends q1,q3; h=1 sends q0,q2
    unsigned sa0 = h ? q[0][0] : q[1][0];
    unsigned sa1 = h ? q[0][1] : q[1][1];
    unsigned sb0 = h ? q[2][0] : q[3][0];
    unsigned sb1 = h ? q[2][1] : q[3][1];
    unsigned ra0 = __shfl_xor(sa0, 32);
    unsigned ra1 = __shfl_xor(sa1, 32);
    unsigned rb0 = __shfl_xor(sb0, 32);
    unsigned rb1 = __shfl_xor(sb1, 32);
    u32x4 w0, w1;
    w0[0] = h ? ra0 : q[0][0];
    w0[1] = h ? ra1 : q[0][1];
    w0[2] = h ? q[1][0] : ra0;
    w0[3] = h ? q[1][1] : ra1;
    w1[0] = h ? rb0 : q[2][0];
    w1[1] = h ? rb1 : q[2][1];
    w1[2] = h ? q[3][0] : rb0;
    w1[3] = h ? q[3][1] : rb1;
    pa0 = *reinterpret_cast<s16x8*>(&w0);
    pa1 = *reinterpret_cast<s16x8*>(&w1);
  };

  auto pv_it = [&]() {
    const u16* gC = smem + OFF_G;
    __builtin_amdgcn_s_setprio(1);
#pragma unroll
    for (int ks = 0; ks < 2; ++ks) {
      s16x8 pa = ks ? pa1 : pa0;
      const int chunk = w * 4 + ks * 2 + h;   // m = chunk*8 + e within tile
#pragma unroll
      for (int ct = 0; ct < 8; ++ct) {
        s16x8 gb = *reinterpret_cast<const s16x8*>(
            &gC[(ct * 32 + l31) * 128 + ((chunk ^ l15) * 8)]);
        oacc[ct] = mfma32(pa, gb, oacc[ct]);
      }
    }
    __builtin_amdgcn_s_setprio(0);
  };

  // prologue
  stage_phi(0);
  __syncthreads();

#pragma unroll 1
  for (int it = 0; it < 32; ++it) {
    stage_g(it * 128);                 // A: G <- g(it); qk reads PHI only
    qk_it();
    __syncthreads();                   // g staged; QK reads of PHI retired
    if (it < 31) stage_phi((it + 1) * 128);   // B: PHI <- phi(it+1)
    pv_it();
    __syncthreads();                   // phi staged; PV reads of G retired
  }

  // ---- L reduce -> iL
  psum += __shfl_xor(psum, 32);
  if (lane < 32) Lp[w * 32 + lane] = psum;
  __syncthreads();
  if (tid < 32)
    iL[tid] = 1.0f / (Lp[tid] + Lp[32 + tid] + Lp[64 + tid] + Lp[96 + tid]);
  __syncthreads();

  // ---- O reduction across waves into LDS (overlay PHI, dead now)
  float* ored = (float*)smem;   // [32][260] f32 = 33280 B
#pragma unroll 1
  for (int step = 0; step < 4; ++step) {
    if (w == step) {
#pragma unroll
      for (int ct = 0; ct < 8; ++ct)
#pragma unroll
        for (int reg = 0; reg < 16; ++reg) {
          int n = (reg & 3) + 8 * (reg >> 2) + 4 * h;
          int c = ct * 32 + l31;
          if (step == 0) ored[n * 260 + c] = oacc[ct][reg];
          else           ored[n * 260 + c] += oacc[ct][reg];
        }
    }
    __syncthreads();
  }

  // ---- normalize + store y (coalesced u16x8)
  u16* yb = y + ((size_t)b * HW_ + n0) * CI_;
  {
    const int n = tid >> 3, cc = (tid & 7) * 32;
    float il = iL[n];
#pragma unroll
    for (int jj = 0; jj < 4; ++jj) {
      f32x4 v0 = *reinterpret_cast<const f32x4*>(&ored[n * 260 + cc + jj * 8]);
      f32x4 v1 = *reinterpret_cast<const f32x4*>(&ored[n * 260 + cc + jj * 8 + 4]);
      u16x8 o;
      o[0] = f2bf(v0[0] * il); o[1] = f2bf(v0[1] * il);
      o[2] = f2bf(v0[2] * il); o[3] = f2bf(v0[3] * il);
      o[4] = f2bf(v1[0] * il); o[5] = f2bf(v1[1] * il);
      o[6] = f2bf(v1[2] * il); o[7] = f2bf(v1[3] * il);
      *reinterpret_cast<u16x8*>(&yb[(size_t)n * CI_ + cc + jj * 8]) = o;
    }
  }
}

// ---------------------------------------------------------------------------
// K4: z = W_w @ y^T + W_b, staged GEMM (M=512, N=16384, K=256).
//   Triple-buffered counted-vmcnt staging like K1.  (R5-proven)
// ---------------------------------------------------------------------------
__global__ __launch_bounds__(256) void k4_wconv(
    const u16* __restrict__ WwB, const u16* __restrict__ y, const float* __restrict__ Wb,
    u16* __restrict__ z, float* __restrict__ zsum, float* __restrict__ zsq)
{
  extern __shared__ u16 sm4[];
  __shared__ float lds_ps[2][128][2];
  const int tid = threadIdx.x;
  const int lane = tid & 63, wid = tid >> 6;
  const int wm = wid >> 1, wn = wid & 1;
  const int l15 = lane & 15, g4 = lane >> 4;

  const int bid = blockIdx.x;            // 512 = 8 xcd * 64
  const int xcd = bid & 7, slot = bid >> 3;
  const int b = xcd >> 1, half = xcd & 1;
  const int mt = slot & 3;
  const int nt = half * 16 + (slot >> 2);
  const int o0 = mt * 128, n0g = nt * 128;

  const int srow = tid >> 2, sch = tid & 3;
  const u16* a_src = WwB + (size_t)(o0 + srow) * CI_ + sch * 8;
  const u16* b_src = y + ((size_t)(b * HW_ + n0g + srow)) * CI_ + sch * 8;

  f32x4 acc[4][4] = {};

  auto stage4 = [&](int buf, int ks) {
    u16* d = sm4 + buf * 8192;
#pragma unroll
    for (int i = 0; i < 2; ++i) {
      gload16(a_src + (size_t)(i * 64) * CI_ + ks * 32, d + (tid + i * 256) * 8);
      gload16(b_src + (size_t)(i * 64) * CI_ + ks * 32, d + 4096 + (tid + i * 256) * 8);
    }
  };
  auto compute4 = [&](int buf) {
    const u16* A = sm4 + buf * 8192;
    const u16* Bt = A + 4096;
    s16x8 afr[4], bfr[4];
#pragma unroll
    for (int mf = 0; mf < 4; ++mf)
      afr[mf] = *reinterpret_cast<const s16x8*>(&A[(wm * 64 + mf * 16 + l15) * 32 + g4 * 8]);
#pragma unroll
    for (int nf = 0; nf < 4; ++nf)
      bfr[nf] = *reinterpret_cast<const s16x8*>(&Bt[(wn * 64 + nf * 16 + l15) * 32 + g4 * 8]);
#pragma unroll
    for (int mf = 0; mf < 4; ++mf)
#pragma unroll
      for (int nf = 0; nf < 4; ++nf)
        acc[mf][nf] = mfma16(afr[mf], bfr[nf], acc[mf][nf]);
  };

  stage4(0, 0); stage4(1, 1);
  int cur = 0;
#pragma unroll 1
  for (int ks = 0; ks < 7; ++ks) {
    asm volatile("s_waitcnt vmcnt(4)" ::: "memory");
    __builtin_amdgcn_s_barrier();
    compute4(cur);
    if (ks < 6) { int nb = cur + 2; if (nb >= 3) nb -= 3; stage4(nb, ks + 2); }
    cur = (cur == 2) ? 0 : cur + 1;
  }
  asm volatile("s_waitcnt vmcnt(0)" ::: "memory");
  __builtin_amdgcn_s_barrier();
  compute4(cur);          // ks = 7
  __syncthreads();

  // bias + BN partials + bf16 transpose store
  u16* lds_t = sm4;
#pragma unroll
  for (int mf = 0; mf < 4; ++mf)
#pragma unroll
    for (int r = 0; r < 4; ++r) {
      const int ol = wm * 64 + mf * 16 + g4 * 4 + r;
      float wb = Wb[o0 + ol];
      float s = 0.f, q = 0.f;
#pragma unroll
      for (int nf = 0; nf < 4; ++nf) {
        float zv = acc[mf][nf][r] + wb;
        s += zv; q += zv * zv;
        lds_t[ol * 136 + wn * 64 + nf * 16 + l15] = f2bf(zv);
      }
      s += __shfl_xor(s, 1); s += __shfl_xor(s, 2); s += __shfl_xor(s, 4); s += __shfl_xor(s, 8);
      q += __shfl_xor(q, 1); q += __shfl_xor(q, 2); q += __shfl_xor(q, 4); q += __shfl_xor(q, 8);
      if (l15 == 0) { lds_ps[wn][ol][0] = s; lds_ps[wn][ol][1] = q; }
    }
  __syncthreads();
  {
    const int m = tid >> 1, hh = tid & 1;
    size_t dst = ((size_t)(b * C_ + o0 + m)) * HW_ + n0g + hh * 64;
#pragma unroll
    for (int j = 0; j < 8; ++j)
      *reinterpret_cast<u16x8*>(&z[dst + j * 8]) =
          *reinterpret_cast<const u16x8*>(&lds_t[m * 136 + hh * 64 + j * 8]);
  }
  if (tid < 128) {
    int col = b * 32 + nt;
    zsum[(size_t)(o0 + tid) * 128 + col] = lds_ps[0][tid][0] + lds_ps[1][tid][0];
    zsq [(size_t)(o0 + tid) * 128 + col] = lds_ps[0][tid][1] + lds_ps[1][tid][1];
  }
}

// ---------------------------------------------------------------------------
// K5: BN stats finalize
// ---------------------------------------------------------------------------
__global__ void k5_bnstat(const float* __restrict__ zsum, const float* __restrict__ zsq,
                          const float* __restrict__ gamma, const float* __restrict__ beta,
                          float* __restrict__ bns, float* __restrict__ bnb)
{
  int ch = blockIdx.x * 256 + threadIdx.x;
  if (ch >= C_) return;
  float s = 0.f, q = 0.f;
  for (int i = 0; i < 128; ++i) { s += zsum[(size_t)ch * 128 + i]; q += zsq[(size_t)ch * 128 + i]; }
  const float inv_n = 1.0f / (B_ * HW_);
  float mean = s * inv_n;
  float var  = q * inv_n - mean * mean;
  float sc = gamma[ch] * rsqrtf(var + 1e-5f);
  bns[ch] = sc;
  bnb[ch] = beta[ch] - mean * sc;
}

// ---------------------------------------------------------------------------
// K6: out = z_bf16*scale[ch] + shift[ch] + x   (8 elems/thread, 4096 blocks)
// ---------------------------------------------------------------------------
__global__ __launch_bounds__(256) void k6_final(
    const u16* __restrict__ z, const float* __restrict__ x,
    const float* __restrict__ bns, const float* __restrict__ bnb,
    float* __restrict__ out)
{
  size_t i = ((size_t)blockIdx.x * 256 + threadIdx.x) * 8;
  int ch = (int)((i >> 12) & 511);
  float sc = bns[ch], sh = bnb[ch];
  u16x8 zv = *reinterpret_cast<const u16x8*>(&z[i]);
  float4 x0 = *reinterpret_cast<const float4*>(&x[i]);
  float4 x1 = *reinterpret_cast<const float4*>(&x[i + 4]);
  float4 o0, o1;
  o0.x = bf2f(zv[0]) * sc + sh + x0.x;
  o0.y = bf2f(zv[1]) * sc + sh + x0.y;
  o0.z = bf2f(zv[2]) * sc + sh + x0.z;
  o0.w = bf2f(zv[3]) * sc + sh + x0.w;
  o1.x = bf2f(zv[4]) * sc + sh + x1.x;
  o1.y = bf2f(zv[5]) * sc + sh + x1.y;
  o1.z = bf2f(zv[6]) * sc + sh + x1.z;
  o1.w = bf2f(zv[7]) * sc + sh + x1.w;
  *reinterpret_cast<float4*>(&out[i])     = o0;
  *reinterpret_cast<float4*>(&out[i + 4]) = o1;
}

// ---------------------------------------------------------------------------
// Workspace layout (peak 33.6 MB):
//   [0,8M):   xT half-buffer (k0x->k1), then y (k3->k4)
//   [8M,16M): thetaT (k1->k3), then zbf low half (k4->k6)
//   [16M,24M):phiT  (k1->k3), then zbf high half
//   [24M,32M):g_s   (k1->k3), then zsum/zsq/bns/bnb (k4->k6)
//   [32M,~33.6M): wB, WwB
// ---------------------------------------------------------------------------
extern "C" void kernel_launch(void* const* d_in, const int* in_sizes, int n_in,
                              void* d_out, int out_size, void* d_ws, size_t ws_size,
                              hipStream_t stream)
{
  (void)in_sizes; (void)n_in; (void)out_size; (void)ws_size;
  const float* x    = (const float*)d_in[0];
  const float* g_w  = (const float*)d_in[1];
  const float* g_b  = (const float*)d_in[2];
  const float* t_w  = (const float*)d_in[3];
  const float* t_b  = (const float*)d_in[4];
  const float* p_w  = (const float*)d_in[5];
  const float* p_b  = (const float*)d_in[6];
  const float* W_w  = (const float*)d_in[7];
  const float* W_b  = (const float*)d_in[8];
  const float* bng  = (const float*)d_in[9];
  const float* bnb_ = (const float*)d_in[10];

  char* ws = (char*)d_ws;
  const size_t M8 = (size_t)8 << 20;
  u16*   xT     = (u16*)(ws + 0);          // 8 MB (per-half)
  u16*   y      = (u16*)(ws + 0);          // overlays xT after k1
  u16*   thetaT = (u16*)(ws + M8);         // 8 MB
  u16*   phiT   = (u16*)(ws + 2 * M8);     // 8 MB
  u16*   g_s    = (u16*)(ws + 3 * M8);     // 8 MB
  u16*   zbf    = (u16*)(ws + M8);         // 16 MB, overlays theta+phi after k3
  float* zsum   = (float*)(ws + 3 * M8);   // overlays g_s after k3
  float* zsq    = (float*)(ws + 3 * M8 + 262144);
  float* bnsV   = (float*)(ws + 3 * M8 + 524288);
  float* bnbV   = (float*)(ws + 3 * M8 + 526336);
  u16*   wB     = (u16*)(ws + 4 * M8);     // 768 KB
  u16*   WwB    = (u16*)(ws + 4 * M8 + 786432);  // 256 KB
  float* out    = (float*)d_out;

  const int k1_lds = 49152;
  const int k3_lds = 131712;
  const int k4_lds = 49152;
  hipFuncSetAttribute(reinterpret_cast<const void*>(k1_proj),
                      hipFuncAttributeMaxDynamicSharedMemorySize, k1_lds);
  hipFuncSetAttribute(reinterpret_cast<const void*>(k3_fused),
                      hipFuncAttributeMaxDynamicSharedMemorySize, k3_lds);
  hipFuncSetAttribute(reinterpret_cast<const void*>(k4_wconv),
                      hipFuncAttributeMaxDynamicSharedMemorySize, k4_lds);

  hipLaunchKernelGGL(k0_wcvt, dim3(256), dim3(256), 0, stream,
                     g_w, t_w, p_w, W_w, wB, WwB);
  for (int half = 0; half < 2; ++half) {
    hipLaunchKernelGGL(k0_xt, dim3(64, 8, 2), dim3(256), 0, stream, x, xT, half * 2);
    hipLaunchKernelGGL(k1_proj, dim3(384), dim3(256), k1_lds, stream,
                       wB, xT, g_b, t_b, p_b, g_s, thetaT, phiT, half);
  }
  hipLaunchKernelGGL(k3_fused, dim3(512), dim3(256), k3_lds, stream,
                     thetaT, phiT, g_s, y);
  hipLaunchKernelGGL(k4_wconv, dim3(512), dim3(256), k4_lds, stream,
                     WwB, y, W_b, zbf, zsum, zsq);
  hipLaunchKernelGGL(k5_bnstat, dim3(2), dim3(256), 0, stream,
                     zsum, zsq, bng, bnb_, bnsV, bnbV);
  hipLaunchKernelGGL(k6_final, dim3(4096), dim3(256), 0, stream,
                     zbf, x, bnsV, bnbV, out);
}

// Round 15
// 197.945 us; speedup vs baseline: 1.5307x; 1.5307x over previous
//
#include <hip/hip_runtime.h>

typedef unsigned short u16;
typedef __attribute__((ext_vector_type(4))) u16 u16x4;
typedef __attribute__((ext_vector_type(8))) u16 u16x8;
typedef __attribute__((ext_vector_type(8))) short s16x8;   // 8 x bf16 (4 VGPRs)
typedef __attribute__((ext_vector_type(4))) float f32x4;
typedef __attribute__((ext_vector_type(16))) float f32x16;

#define B_  4
#define C_  512
#define CI_ 256
#define HW_ 4096

static __device__ __forceinline__ u16 f2bf(float f) {
  unsigned u = __float_as_uint(f);
  return (u16)((u + 0x7FFFu + ((u >> 16) & 1u)) >> 16);   // RNE
}
static __device__ __forceinline__ float bf2f(u16 h) {
  return __uint_as_float(((unsigned)h) << 16);
}

static __device__ __forceinline__ f32x4 mfma16(s16x8 a, s16x8 b, f32x4 c) {
  return __builtin_amdgcn_mfma_f32_16x16x32_bf16(a, b, c, 0, 0, 0);
}
static __device__ __forceinline__ f32x16 mfma32(s16x8 a, s16x8 b, f32x16 c) {
  return __builtin_amdgcn_mfma_f32_32x32x16_bf16(a, b, c, 0, 0, 0);
}

typedef __attribute__((address_space(3))) unsigned int as3_u32;
typedef const __attribute__((address_space(1))) unsigned int as1_u32;
static __device__ __forceinline__ void gload16(const u16* g, u16* l) {
  __builtin_amdgcn_global_load_lds((as1_u32*)g, (as3_u32*)l, 16, 0, 0);
}

// ---------------------------------------------------------------------------
// K0w: convert weights to bf16.  wB[768][512] = {g_w, theta_w, phi_w};
//      WwB[512][256] = W_w.
// ---------------------------------------------------------------------------
__global__ __launch_bounds__(256) void k0_wcvt(
    const float* __restrict__ wg, const float* __restrict__ wt,
    const float* __restrict__ wp, const float* __restrict__ Ww,
    u16* __restrict__ wB, u16* __restrict__ WwB)
{
  int idx = (blockIdx.x * 256 + threadIdx.x) * 8;   // over 524288 elems
  const float* src;
  u16* dst;
  if (idx < 393216) {
    int r = idx >> 17;                 // 0..2 region of 131072
    src = (r == 0 ? wg : r == 1 ? wt : wp) + (idx & 131071);
    dst = wB + idx;
  } else {
    src = Ww + (idx - 393216);
    dst = WwB + (idx - 393216);
  }
  float4 v0 = *reinterpret_cast<const float4*>(src);
  float4 v1 = *reinterpret_cast<const float4*>(src + 4);
  u16x8 h;
  h[0] = f2bf(v0.x); h[1] = f2bf(v0.y); h[2] = f2bf(v0.z); h[3] = f2bf(v0.w);
  h[4] = f2bf(v1.x); h[5] = f2bf(v1.y); h[6] = f2bf(v1.z); h[7] = f2bf(v1.w);
  *reinterpret_cast<u16x8*>(dst) = h;
}

// ---------------------------------------------------------------------------
// K0x: x (b0+z) (C,HW) f32 -> xT (z,HW,C) bf16 token-major; 64x64 LDS tiles.
// ---------------------------------------------------------------------------
__global__ __launch_bounds__(256) void k0_xt(
    const float* __restrict__ x, u16* __restrict__ xT, int b0)
{
  __shared__ u16 lds[64][72];   // [c][n]
  const int tid = threadIdx.x;
  const int n0 = blockIdx.x * 64, c0 = blockIdx.y * 64;
  const int bl = blockIdx.z;            // 0..1 local
  const int b = b0 + bl;
  const int nc = (tid & 15) * 4;
#pragma unroll
  for (int i = 0; i < 4; ++i) {
    int cr = (tid >> 4) + i * 16;
    float4 v = *reinterpret_cast<const float4*>(
        &x[((size_t)(b * C_ + c0 + cr)) * HW_ + n0 + nc]);
    u16x4 h; h[0] = f2bf(v.x); h[1] = f2bf(v.y); h[2] = f2bf(v.z); h[3] = f2bf(v.w);
    *reinterpret_cast<u16x4*>(&lds[cr][nc]) = h;
  }
  __syncthreads();
  const int n = tid & 63, cg = tid >> 6;
  u16x8 o0, o1;
#pragma unroll
  for (int j = 0; j < 8; ++j) { o0[j] = lds[cg * 16 + j][n]; o1[j] = lds[cg * 16 + 8 + j][n]; }
  size_t dstb = ((size_t)bl * HW_ + n0 + n) * C_ + c0 + cg * 16;
  *reinterpret_cast<u16x8*>(&xT[dstb])     = o0;
  *reinterpret_cast<u16x8*>(&xT[dstb + 8]) = o1;
}

// ---------------------------------------------------------------------------
// K1: fused projections as one staged NT GEMM (per 2-batch half).
//   tile 128x128, BK=32, triple-buffered counted-vmcnt staging.  (R5-proven)
// ---------------------------------------------------------------------------
__global__ __launch_bounds__(256) void k1_proj(
    const u16* __restrict__ wB, const u16* __restrict__ xT,
    const float* __restrict__ bg, const float* __restrict__ bt, const float* __restrict__ bp,
    u16* __restrict__ g_s, u16* __restrict__ thetaT, u16* __restrict__ phiT, int half)
{
  extern __shared__ u16 sm1[];   // 3 bufs of 8192 u16: A@+0 (4096), B@+4096
  const int tid = threadIdx.x;
  const int lane = tid & 63, wid = tid >> 6;
  const int wm = wid >> 1, wn = wid & 1;
  const int l15 = lane & 15, g4 = lane >> 4;

  const int bid = blockIdx.x;            // 384 = 12 * 32
  const int r12 = bid % 12;
  const int nt = bid / 12;               // 0..31
  const int mt = r12 >> 1;               // 0..5 (p = mt>>1)
  const int bl = r12 & 1;                // local batch
  const int b = half * 2 + bl;
  const int m0 = mt * 128, n0g = nt * 128;
  const int p = mt >> 1;

  const u16* xb = xT + (size_t)bl * HW_ * C_;

  const int srow = tid >> 2, sch = tid & 3;
  const u16* a_src = wB + (size_t)(m0 + srow) * C_ + sch * 8;
  const u16* b_src = xb + (size_t)(n0g + srow) * C_ + sch * 8;

  f32x4 acc[4][4] = {};

  auto stage1 = [&](int buf, int ks) {
    u16* d = sm1 + buf * 8192;
#pragma unroll
    for (int i = 0; i < 2; ++i) {
      gload16(a_src + (size_t)(i * 64) * C_ + ks * 32, d + (tid + i * 256) * 8);
      gload16(b_src + (size_t)(i * 64) * C_ + ks * 32, d + 4096 + (tid + i * 256) * 8);
    }
  };
  auto compute1 = [&](int buf) {
    const u16* A = sm1 + buf * 8192;
    const u16* Bt = A + 4096;
    s16x8 afr[4], bfr[4];
#pragma unroll
    for (int mf = 0; mf < 4; ++mf)
      afr[mf] = *reinterpret_cast<const s16x8*>(&A[(wm * 64 + mf * 16 + l15) * 32 + g4 * 8]);
#pragma unroll
    for (int nf = 0; nf < 4; ++nf)
      bfr[nf] = *reinterpret_cast<const s16x8*>(&Bt[(wn * 64 + nf * 16 + l15) * 32 + g4 * 8]);
#pragma unroll
    for (int mf = 0; mf < 4; ++mf)
#pragma unroll
      for (int nf = 0; nf < 4; ++nf)
        acc[mf][nf] = mfma16(afr[mf], bfr[nf], acc[mf][nf]);
  };

  stage1(0, 0); stage1(1, 1);
  int cur = 0;
#pragma unroll 1
  for (int ks = 0; ks < 15; ++ks) {
    asm volatile("s_waitcnt vmcnt(4)" ::: "memory");
    __builtin_amdgcn_s_barrier();
    compute1(cur);
    if (ks < 14) { int nb = cur + 2; if (nb >= 3) nb -= 3; stage1(nb, ks + 2); }
    cur = (cur == 2) ? 0 : cur + 1;
  }
  asm volatile("s_waitcnt vmcnt(0)" ::: "memory");
  __builtin_amdgcn_s_barrier();
  compute1(cur);          // ks = 15
  __syncthreads();        // all waves done reading bufs before lds_t overlay

  const float* bias = (p == 0) ? bg : (p == 1) ? bt : bp;
  const int cib = (mt & 1) * 128;
#pragma unroll
  for (int mf = 0; mf < 4; ++mf)
#pragma unroll
    for (int r = 0; r < 4; ++r) {
      float bv = bias[cib + wm * 64 + mf * 16 + g4 * 4 + r];
#pragma unroll
      for (int nf = 0; nf < 4; ++nf) acc[mf][nf][r] += bv;
    }

  if (p == 0) {
    // g: channel-major store via LDS transpose.  lds_t [128][136] u16
    u16* lds_t = sm1;
#pragma unroll
    for (int mf = 0; mf < 4; ++mf)
#pragma unroll
      for (int nf = 0; nf < 4; ++nf)
#pragma unroll
        for (int r = 0; r < 4; ++r)
          lds_t[(wm * 64 + mf * 16 + g4 * 4 + r) * 136 + wn * 64 + nf * 16 + l15] =
              f2bf(acc[mf][nf][r]);
    __syncthreads();
    const int m = tid >> 1, hh = tid & 1;
    size_t dst = ((size_t)b * CI_ + cib + m) * HW_ + n0g + hh * 64;
#pragma unroll
    for (int j = 0; j < 8; ++j)
      *reinterpret_cast<u16x8*>(&g_s[dst + j * 8]) =
          *reinterpret_cast<const u16x8*>(&lds_t[m * 136 + hh * 64 + j * 8]);
  } else {
    u16* outp = (p == 1) ? thetaT : phiT;
#pragma unroll
    for (int mf = 0; mf < 4; ++mf)
#pragma unroll
      for (int nf = 0; nf < 4; ++nf) {
        u16x4 h;
#pragma unroll
        for (int r = 0; r < 4; ++r) h[r] = f2bf(acc[mf][nf][r]);
        int n = n0g + wn * 64 + nf * 16 + l15;
        *reinterpret_cast<u16x4*>(
            &outp[((size_t)b * HW_ + n) * CI_ + cib + wm * 64 + mf * 16 + g4 * 4]) = h;
      }
  }
}

// ---------------------------------------------------------------------------
// K3: fused single-pass attention on 32x32x16 MFMA — the R11-verified best.
//  256 blocks x 512 thr (8 waves), n-tile 64, m-tile 128, 32 iterations.
//  LDS: PHI [128][256] 64KB + G [256][128] 64KB + P [64][128] 16KB + L.
//  All tiles XOR-swizzled at 16B-chunk x (row&15) -> ~conflict-free.
//  Conservative 2-sync skeleton:
//    A_it: { stage_g(it); qk(it) }   sync
//    B_it: { stage_phi(it+1); pv(it) } sync
// ---------------------------------------------------------------------------
#define OFF_PHI  0        // [128][256] u16 (65536 B)
#define OFF_G    32768    // [256][128] u16 (65536 B)
#define OFF_P    65536    // [64][128] u16 (16384 B)
#define OFF_LP   73728    // f32: Lp[8][32] + iL[64] -> total 148736 B

__global__ __launch_bounds__(512, 2) void k3_fused(
    const u16* __restrict__ thetaT, const u16* __restrict__ phiT,
    const u16* __restrict__ g_s, u16* __restrict__ y)
{
  extern __shared__ u16 smem[];
  float* Lp = (float*)(smem + OFF_LP);   // [8][32]
  float* iL = Lp + 256;                  // [64]

  const int tid = threadIdx.x;
  const int lane = tid & 63, w = tid >> 6;   // w in 0..7
  const int l31 = lane & 31, h = lane >> 5;  // h in 0..1
  const int l15 = lane & 15;

  const int bid = blockIdx.x;            // 256 = 8 xcd * 32
  const int xcd = bid & 7, slot = bid >> 3;
  const int b  = xcd >> 1;
  const int n0 = ((xcd & 1) * 32 + slot) * 64;   // 64 n-tiles of 64 per batch

  const int mh = w >> 1, nh = w & 1;    // QK roles
  const int cq = w >> 1, nh2 = w & 1;   // PV roles

  const u16* thb = thetaT + (size_t)b * HW_ * CI_;
  const u16* phb = phiT   + (size_t)b * HW_ * CI_;
  const u16* gsb = g_s    + (size_t)b * CI_ * HW_;

  // theta hoist: wave's 32 cols, 16 k-steps of 16 -> 64 VGPR (B operand)
  s16x8 thfr[16];
#pragma unroll
  for (int cs = 0; cs < 16; ++cs)
    thfr[cs] = *reinterpret_cast<const s16x8*>(
        &thb[(size_t)(n0 + nh * 32 + l31) * CI_ + cs * 16 + h * 8]);

  // staging maps (pre-swizzled global source, linear LDS dest = tid*16B)
  const int prow = tid >> 5, pj = tid & 31;   // phi: 16 rows/issue, 32 chunks
  const int grow = tid >> 4, gj = tid & 15;   // g: 32 rows/issue, 16 chunks
  const u16* ph_src = phb + (size_t)prow * CI_ + ((pj ^ prow) * 8);       // prow = m&15
  const u16* g_src  = gsb + (size_t)grow * HW_ + ((gj ^ (grow & 15)) * 8);
  const int ph_do = prow * 256 + pj * 8;
  const int g_do  = grow * 128 + gj * 8;

  auto stage_phi = [&](int mt) {
#pragma unroll
    for (int i = 0; i < 8; ++i)
      gload16(ph_src + (size_t)(mt + i * 16) * CI_, smem + OFF_PHI + ph_do + i * 4096);
  };
  auto stage_g = [&](int mt) {
#pragma unroll
    for (int i = 0; i < 8; ++i)
      gload16(g_src + mt + (size_t)(i * 32) * HW_, smem + OFF_G + g_do + i * 4096);
  };

  f32x16 oacc[2] = {};
  float psum = 0.f;

  auto qk_it = [&]() {
    const u16* phc = smem + OFF_PHI;
    u16* pb = smem + OFF_P;
    f32x16 acc = {};
    __builtin_amdgcn_s_setprio(1);
#pragma unroll
    for (int cs = 0; cs < 16; ++cs) {
      s16x8 a = *reinterpret_cast<const s16x8*>(
          &phc[(mh * 32 + l31) * 256 + (((cs * 2 + h) ^ l15) * 8)]);
      acc = mfma32(a, thfr[cs], acc);
    }
    __builtin_amdgcn_s_setprio(0);
    const int nloc = nh * 32 + l31;
#pragma unroll
    for (int g = 0; g < 4; ++g) {
      u16x4 pk;
#pragma unroll
      for (int r = 0; r < 4; ++r) {
        float e = __expf(acc[4 * g + r] * 0.0625f);
        psum += e;
        pk[r] = f2bf(e);
      }
      *reinterpret_cast<u16x4*>(
          &pb[nloc * 128 + (((mh * 4 + g) ^ l15) * 8) + h * 4]) = pk;
    }
  };
  auto pv_it = [&]() {
    const u16* pb = smem + OFF_P;
    const u16* gC = smem + OFF_G;
    const int nloc = nh2 * 32 + l31;
    __builtin_amdgcn_s_setprio(1);
#pragma unroll
    for (int ks = 0; ks < 8; ++ks) {
      s16x8 pa = *reinterpret_cast<const s16x8*>(
          &pb[nloc * 128 + (((ks * 2 + h) ^ l15) * 8)]);
#pragma unroll
      for (int ct = 0; ct < 2; ++ct) {
        int c = cq * 64 + ct * 32 + l31;
        s16x8 gb = *reinterpret_cast<const s16x8*>(
            &gC[c * 128 + (((ks * 2 + h) ^ l15) * 8)]);
        oacc[ct] = mfma32(pa, gb, oacc[ct]);
      }
    }
    __builtin_amdgcn_s_setprio(0);
  };

  // prologue: PHI <- phi(0)
  stage_phi(0);
  __syncthreads();

#pragma unroll 1
  for (int it = 0; it < 32; ++it) {
    stage_g(it * 128);                 // A: G <- g(it); qk reads PHI only
    qk_it();
    __syncthreads();                   // g staged + P written
    if (it < 31) stage_phi((it + 1) * 128);   // B: PHI <- phi(it+1); pv reads P,G
    pv_it();
    __syncthreads();                   // phi staged + P/G reads retired
  }

  // epilogue: L reduce -> iL; normalize + store y
  psum += __shfl_xor(psum, 32);
  if (lane < 32) Lp[w * 32 + lane] = psum;
  __syncthreads();
  if (tid < 64) {
    int nhh = tid >> 5, j = tid & 31;
    iL[tid] = 1.0f / (Lp[(0 * 2 + nhh) * 32 + j] + Lp[(1 * 2 + nhh) * 32 + j] +
                      Lp[(2 * 2 + nhh) * 32 + j] + Lp[(3 * 2 + nhh) * 32 + j]);
  }
  __syncthreads();

  u16* yb = y + ((size_t)b * HW_ + n0) * CI_;
#pragma unroll
  for (int ct = 0; ct < 2; ++ct) {
    int c = cq * 64 + ct * 32 + l31;
#pragma unroll
    for (int reg = 0; reg < 16; ++reg) {
      int nl = nh2 * 32 + (reg & 3) + 8 * (reg >> 2) + 4 * h;
      yb[(size_t)nl * CI_ + c] = f2bf(oacc[ct][reg] * iL[nl]);
    }
  }
}

// ---------------------------------------------------------------------------
// K4: z = W_w @ y^T + W_b on 32x32x16 MFMA, fully LDS-resident K.
//  512 blocks x 256 thr (4 waves).  Block tile: 128 o x 128 n, K=256 staged
//  ONCE (A 64KB + B 64KB = 128KB dynamic LDS), single sync, 64 mfma32/wave.
//  Staging/fragment swizzle maps identical in form to k3's verified ones
//  (XOR 16B-chunk with row&15; E/O source bases for the 8-row issue stride).
//  Epilogue: bias + BN partials (zsum/zsq layout unchanged -> k5 untouched)
//  + bf16 z channel-major via lds_t transpose (k1 pattern).
// ---------------------------------------------------------------------------
#define K4_A 0        // [128][256] u16 (65536 B)
#define K4_B 32768    // [128][256] u16 (65536 B) -> dynamic total 131072 B

__global__ __launch_bounds__(256, 1) void k4_wconv(
    const u16* __restrict__ WwB, const u16* __restrict__ y, const float* __restrict__ Wb,
    u16* __restrict__ z, float* __restrict__ zsum, float* __restrict__ zsq)
{
  extern __shared__ u16 sm4[];
  __shared__ float lds_ps[2][128][2];
  const int tid = threadIdx.x;
  const int lane = tid & 63, w = tid >> 6;   // 4 waves
  const int wo = w >> 1, wn2 = w & 1;        // wave tile: o-half 64, n-half 64
  const int l31 = lane & 31, h = lane >> 5;
  const int l15 = lane & 15;

  const int bid = blockIdx.x;            // 512 = 8 xcd * 64
  const int xcd = bid & 7, slot = bid >> 3;
  const int b = xcd >> 1, halfq = xcd & 1;
  const int mt = slot & 3;
  const int nt = halfq * 16 + (slot >> 2);
  const int o0 = mt * 128, n0g = nt * 128;

  // staging: 16 issues each for A and B; issue i covers rows i*8 + (tid>>5)
  const int prow = tid >> 5, pj = tid & 31;     // prow 0..7, 32 chunks/row
  const u16* aE = WwB + (size_t)(o0 + prow) * CI_ + ((pj ^ prow) * 8);
  const u16* aO = WwB + (size_t)(o0 + prow) * CI_ + ((pj ^ prow ^ 8) * 8);
  const u16* bE = y + ((size_t)(b * HW_ + n0g + prow)) * CI_ + ((pj ^ prow) * 8);
  const u16* bO = y + ((size_t)(b * HW_ + n0g + prow)) * CI_ + ((pj ^ prow ^ 8) * 8);
  const int s_do = prow * 256 + pj * 8;

#pragma unroll
  for (int i = 0; i < 16; ++i) {
    const u16* sa = (i & 1) ? aO : aE;
    const u16* sb = (i & 1) ? bO : bE;
    gload16(sa + (size_t)(i * 8) * CI_, sm4 + K4_A + s_do + i * 2048);
    gload16(sb + (size_t)(i * 8) * CI_, sm4 + K4_B + s_do + i * 2048);
  }
  __syncthreads();

  f32x16 acc[2][2] = {};   // [ot][nt2]
  {
    const u16* A = sm4 + K4_A;
    const u16* Bt = sm4 + K4_B;
#pragma unroll
    for (int cs = 0; cs < 16; ++cs) {
      s16x8 a0 = *reinterpret_cast<const s16x8*>(
          &A[(wo * 64 + 0 + l31) * 256 + (((cs * 2 + h) ^ l15) * 8)]);
      s16x8 a1 = *reinterpret_cast<const s16x8*>(
          &A[(wo * 64 + 32 + l31) * 256 + (((cs * 2 + h) ^ l15) * 8)]);
      s16x8 b0 = *reinterpret_cast<const s16x8*>(
          &Bt[(wn2 * 64 + 0 + l31) * 256 + (((cs * 2 + h) ^ l15) * 8)]);
      s16x8 b1 = *reinterpret_cast<const s16x8*>(
          &Bt[(wn2 * 64 + 32 + l31) * 256 + (((cs * 2 + h) ^ l15) * 8)]);
      acc[0][0] = mfma32(a0, b0, acc[0][0]);
      acc[0][1] = mfma32(a0, b1, acc[0][1]);
      acc[1][0] = mfma32(a1, b0, acc[1][0]);
      acc[1][1] = mfma32(a1, b1, acc[1][1]);
    }
  }
  __syncthreads();   // all A/B reads retired before lds_t overlay

  // bias + BN partials + bf16 store staging.  lds_t [128][136] u16
  u16* lds_t = sm4;
#pragma unroll
  for (int ot = 0; ot < 2; ++ot)
#pragma unroll
    for (int reg = 0; reg < 16; ++reg) {
      const int ol = wo * 64 + ot * 32 + (reg & 3) + 8 * (reg >> 2) + 4 * h;
      float wb = Wb[o0 + ol];
      float z0 = acc[ot][0][reg] + wb;
      float z1 = acc[ot][1][reg] + wb;
      lds_t[ol * 136 + wn2 * 64 + l31]      = f2bf(z0);
      lds_t[ol * 136 + wn2 * 64 + 32 + l31] = f2bf(z1);
      float s = z0 + z1, q = z0 * z0 + z1 * z1;
      s += __shfl_xor(s, 1); s += __shfl_xor(s, 2); s += __shfl_xor(s, 4);
      s += __shfl_xor(s, 8); s += __shfl_xor(s, 16);
      q += __shfl_xor(q, 1); q += __shfl_xor(q, 2); q += __shfl_xor(q, 4);
      q += __shfl_xor(q, 8); q += __shfl_xor(q, 16);
      if (l31 == 0) { lds_ps[wn2][ol][0] = s; lds_ps[wn2][ol][1] = q; }
    }
  __syncthreads();
  {
    const int m = tid >> 1, hh = tid & 1;
    size_t dst = ((size_t)(b * C_ + o0 + m)) * HW_ + n0g + hh * 64;
#pragma unroll
    for (int j = 0; j < 8; ++j)
      *reinterpret_cast<u16x8*>(&z[dst + j * 8]) =
          *reinterpret_cast<const u16x8*>(&lds_t[m * 136 + hh * 64 + j * 8]);
  }
  if (tid < 128) {
    int col = b * 32 + nt;
    zsum[(size_t)(o0 + tid) * 128 + col] = lds_ps[0][tid][0] + lds_ps[1][tid][0];
    zsq [(size_t)(o0 + tid) * 128 + col] = lds_ps[0][tid][1] + lds_ps[1][tid][1];
  }
}

// ---------------------------------------------------------------------------
// K5: BN stats finalize
// ---------------------------------------------------------------------------
__global__ void k5_bnstat(const float* __restrict__ zsum, const float* __restrict__ zsq,
                          const float* __restrict__ gamma, const float* __restrict__ beta,
                          float* __restrict__ bns, float* __restrict__ bnb)
{
  int ch = blockIdx.x * 256 + threadIdx.x;
  if (ch >= C_) return;
  float s = 0.f, q = 0.f;
  for (int i = 0; i < 128; ++i) { s += zsum[(size_t)ch * 128 + i]; q += zsq[(size_t)ch * 128 + i]; }
  const float inv_n = 1.0f / (B_ * HW_);
  float mean = s * inv_n;
  float var  = q * inv_n - mean * mean;
  float sc = gamma[ch] * rsqrtf(var + 1e-5f);
  bns[ch] = sc;
  bnb[ch] = beta[ch] - mean * sc;
}

// ---------------------------------------------------------------------------
// K6: out = z_bf16*scale[ch] + shift[ch] + x   (8 elems/thread, 4096 blocks)
// ---------------------------------------------------------------------------
__global__ __launch_bounds__(256) void k6_final(
    const u16* __restrict__ z, const float* __restrict__ x,
    const float* __restrict__ bns, const float* __restrict__ bnb,
    float* __restrict__ out)
{
  size_t i = ((size_t)blockIdx.x * 256 + threadIdx.x) * 8;
  int ch = (int)((i >> 12) & 511);
  float sc = bns[ch], sh = bnb[ch];
  u16x8 zv = *reinterpret_cast<const u16x8*>(&z[i]);
  float4 x0 = *reinterpret_cast<const float4*>(&x[i]);
  float4 x1 = *reinterpret_cast<const float4*>(&x[i + 4]);
  float4 o0, o1;
  o0.x = bf2f(zv[0]) * sc + sh + x0.x;
  o0.y = bf2f(zv[1]) * sc + sh + x0.y;
  o0.z = bf2f(zv[2]) * sc + sh + x0.z;
  o0.w = bf2f(zv[3]) * sc + sh + x0.w;
  o1.x = bf2f(zv[4]) * sc + sh + x1.x;
  o1.y = bf2f(zv[5]) * sc + sh + x1.y;
  o1.z = bf2f(zv[6]) * sc + sh + x1.z;
  o1.w = bf2f(zv[7]) * sc + sh + x1.w;
  *reinterpret_cast<float4*>(&out[i])     = o0;
  *reinterpret_cast<float4*>(&out[i + 4]) = o1;
}

// ---------------------------------------------------------------------------
// Workspace layout (peak 33.6 MB):
//   [0,8M):   xT half-buffer (k0x->k1), then y (k3->k4)
//   [8M,16M): thetaT (k1->k3), then zbf low half (k4->k6)
//   [16M,24M):phiT  (k1->k3), then zbf high half
//   [24M,32M):g_s   (k1->k3), then zsum/zsq/bns/bnb (k4->k6)
//   [32M,~33.6M): wB, WwB
// ---------------------------------------------------------------------------
extern "C" void kernel_launch(void* const* d_in, const int* in_sizes, int n_in,
                              void* d_out, int out_size, void* d_ws, size_t ws_size,
                              hipStream_t stream)
{
  (void)in_sizes; (void)n_in; (void)out_size; (void)ws_size;
  const float* x    = (const float*)d_in[0];
  const float* g_w  = (const float*)d_in[1];
  const float* g_b  = (const float*)d_in[2];
  const float* t_w  = (const float*)d_in[3];
  const float* t_b  = (const float*)d_in[4];
  const float* p_w  = (const float*)d_in[5];
  const float* p_b  = (const float*)d_in[6];
  const float* W_w  = (const float*)d_in[7];
  const float* W_b  = (const float*)d_in[8];
  const float* bng  = (const float*)d_in[9];
  const float* bnb_ = (const float*)d_in[10];

  char* ws = (char*)d_ws;
  const size_t M8 = (size_t)8 << 20;
  u16*   xT     = (u16*)(ws + 0);          // 8 MB (per-half)
  u16*   y      = (u16*)(ws + 0);          // overlays xT after k1
  u16*   thetaT = (u16*)(ws + M8);         // 8 MB
  u16*   phiT   = (u16*)(ws + 2 * M8);     // 8 MB
  u16*   g_s    = (u16*)(ws + 3 * M8);     // 8 MB
  u16*   zbf    = (u16*)(ws + M8);         // 16 MB, overlays theta+phi after k3
  float* zsum   = (float*)(ws + 3 * M8);   // overlays g_s after k3
  float* zsq    = (float*)(ws + 3 * M8 + 262144);
  float* bnsV   = (float*)(ws + 3 * M8 + 524288);
  float* bnbV   = (float*)(ws + 3 * M8 + 526336);
  u16*   wB     = (u16*)(ws + 4 * M8);     // 768 KB
  u16*   WwB    = (u16*)(ws + 4 * M8 + 786432);  // 256 KB
  float* out    = (float*)d_out;

  const int k1_lds = 49152;
  const int k3_lds = 148736;
  const int k4_lds = 131072;
  hipFuncSetAttribute(reinterpret_cast<const void*>(k1_proj),
                      hipFuncAttributeMaxDynamicSharedMemorySize, k1_lds);
  hipFuncSetAttribute(reinterpret_cast<const void*>(k3_fused),
                      hipFuncAttributeMaxDynamicSharedMemorySize, k3_lds);
  hipFuncSetAttribute(reinterpret_cast<const void*>(k4_wconv),
                      hipFuncAttributeMaxDynamicSharedMemorySize, k4_lds);

  hipLaunchKernelGGL(k0_wcvt, dim3(256), dim3(256), 0, stream,
                     g_w, t_w, p_w, W_w, wB, WwB);
  for (int half = 0; half < 2; ++half) {
    hipLaunchKernelGGL(k0_xt, dim3(64, 8, 2), dim3(256), 0, stream, x, xT, half * 2);
    hipLaunchKernelGGL(k1_proj, dim3(384), dim3(256), k1_lds, stream,
                       wB, xT, g_b, t_b, p_b, g_s, thetaT, phiT, half);
  }
  hipLaunchKernelGGL(k3_fused, dim3(256), dim3(512), k3_lds, stream,
                     thetaT, phiT, g_s, y);
  hipLaunchKernelGGL(k4_wconv, dim3(512), dim3(256), k4_lds, stream,
                     WwB, y, W_b, zbf, zsum, zsq);
  hipLaunchKernelGGL(k5_bnstat, dim3(2), dim3(256), 0, stream,
                     zsum, zsq, bng, bnb_, bnsV, bnbV);
  hipLaunchKernelGGL(k6_final, dim3(4096), dim3(256), 0, stream,
                     zbf, x, bnsV, bnbV, out);
}

// Round 16
// 187.208 us; speedup vs baseline: 1.6184x; 1.0573x over previous
//
#include <hip/hip_runtime.h>

typedef unsigned short u16;
typedef __attribute__((ext_vector_type(4))) u16 u16x4;
typedef __attribute__((ext_vector_type(8))) u16 u16x8;
typedef __attribute__((ext_vector_type(8))) short s16x8;   // 8 x bf16 (4 VGPRs)
typedef __attribute__((ext_vector_type(4))) float f32x4;
typedef __attribute__((ext_vector_type(16))) float f32x16;

#define B_  4
#define C_  512
#define CI_ 256
#define HW_ 4096

static __device__ __forceinline__ u16 f2bf(float f) {
  unsigned u = __float_as_uint(f);
  return (u16)((u + 0x7FFFu + ((u >> 16) & 1u)) >> 16);   // RNE
}
static __device__ __forceinline__ float bf2f(u16 h) {
  return __uint_as_float(((unsigned)h) << 16);
}

static __device__ __forceinline__ f32x4 mfma16(s16x8 a, s16x8 b, f32x4 c) {
  return __builtin_amdgcn_mfma_f32_16x16x32_bf16(a, b, c, 0, 0, 0);
}
static __device__ __forceinline__ f32x16 mfma32(s16x8 a, s16x8 b, f32x16 c) {
  return __builtin_amdgcn_mfma_f32_32x32x16_bf16(a, b, c, 0, 0, 0);
}

typedef __attribute__((address_space(3))) unsigned int as3_u32;
typedef const __attribute__((address_space(1))) unsigned int as1_u32;
static __device__ __forceinline__ void gload16(const u16* g, u16* l) {
  __builtin_amdgcn_global_load_lds((as1_u32*)g, (as3_u32*)l, 16, 0, 0);
}

// ---------------------------------------------------------------------------
// K0w: convert weights to bf16.  wB[768][512] = {g_w, theta_w, phi_w};
//      WwB[512][256] = W_w.
// ---------------------------------------------------------------------------
__global__ __launch_bounds__(256) void k0_wcvt(
    const float* __restrict__ wg, const float* __restrict__ wt,
    const float* __restrict__ wp, const float* __restrict__ Ww,
    u16* __restrict__ wB, u16* __restrict__ WwB)
{
  int idx = (blockIdx.x * 256 + threadIdx.x) * 8;   // over 524288 elems
  const float* src;
  u16* dst;
  if (idx < 393216) {
    int r = idx >> 17;                 // 0..2 region of 131072
    src = (r == 0 ? wg : r == 1 ? wt : wp) + (idx & 131071);
    dst = wB + idx;
  } else {
    src = Ww + (idx - 393216);
    dst = WwB + (idx - 393216);
  }
  float4 v0 = *reinterpret_cast<const float4*>(src);
  float4 v1 = *reinterpret_cast<const float4*>(src + 4);
  u16x8 h;
  h[0] = f2bf(v0.x); h[1] = f2bf(v0.y); h[2] = f2bf(v0.z); h[3] = f2bf(v0.w);
  h[4] = f2bf(v1.x); h[5] = f2bf(v1.y); h[6] = f2bf(v1.z); h[7] = f2bf(v1.w);
  *reinterpret_cast<u16x8*>(dst) = h;
}

// ---------------------------------------------------------------------------
// K0x: x (b0+z) (C,HW) f32 -> xT (z,HW,C) bf16 token-major; 64x64 LDS tiles.
// ---------------------------------------------------------------------------
__global__ __launch_bounds__(256) void k0_xt(
    const float* __restrict__ x, u16* __restrict__ xT, int b0)
{
  __shared__ u16 lds[64][72];   // [c][n]
  const int tid = threadIdx.x;
  const int n0 = blockIdx.x * 64, c0 = blockIdx.y * 64;
  const int bl = blockIdx.z;            // 0..1 local
  const int b = b0 + bl;
  const int nc = (tid & 15) * 4;
#pragma unroll
  for (int i = 0; i < 4; ++i) {
    int cr = (tid >> 4) + i * 16;
    float4 v = *reinterpret_cast<const float4*>(
        &x[((size_t)(b * C_ + c0 + cr)) * HW_ + n0 + nc]);
    u16x4 h; h[0] = f2bf(v.x); h[1] = f2bf(v.y); h[2] = f2bf(v.z); h[3] = f2bf(v.w);
    *reinterpret_cast<u16x4*>(&lds[cr][nc]) = h;
  }
  __syncthreads();
  const int n = tid & 63, cg = tid >> 6;
  u16x8 o0, o1;
#pragma unroll
  for (int j = 0; j < 8; ++j) { o0[j] = lds[cg * 16 + j][n]; o1[j] = lds[cg * 16 + 8 + j][n]; }
  size_t dstb = ((size_t)bl * HW_ + n0 + n) * C_ + c0 + cg * 16;
  *reinterpret_cast<u16x8*>(&xT[dstb])     = o0;
  *reinterpret_cast<u16x8*>(&xT[dstb + 8]) = o1;
}

// ---------------------------------------------------------------------------
// K1: fused projections as one staged NT GEMM (per 2-batch half).
//   tile 128x128, BK=32, triple-buffered counted-vmcnt staging.  (R5-proven)
// ---------------------------------------------------------------------------
__global__ __launch_bounds__(256) void k1_proj(
    const u16* __restrict__ wB, const u16* __restrict__ xT,
    const float* __restrict__ bg, const float* __restrict__ bt, const float* __restrict__ bp,
    u16* __restrict__ g_s, u16* __restrict__ thetaT, u16* __restrict__ phiT, int half)
{
  extern __shared__ u16 sm1[];   // 3 bufs of 8192 u16: A@+0 (4096), B@+4096
  const int tid = threadIdx.x;
  const int lane = tid & 63, wid = tid >> 6;
  const int wm = wid >> 1, wn = wid & 1;
  const int l15 = lane & 15, g4 = lane >> 4;

  const int bid = blockIdx.x;            // 384 = 12 * 32
  const int r12 = bid % 12;
  const int nt = bid / 12;               // 0..31
  const int mt = r12 >> 1;               // 0..5 (p = mt>>1)
  const int bl = r12 & 1;                // local batch
  const int b = half * 2 + bl;
  const int m0 = mt * 128, n0g = nt * 128;
  const int p = mt >> 1;

  const u16* xb = xT + (size_t)bl * HW_ * C_;

  const int srow = tid >> 2, sch = tid & 3;
  const u16* a_src = wB + (size_t)(m0 + srow) * C_ + sch * 8;
  const u16* b_src = xb + (size_t)(n0g + srow) * C_ + sch * 8;

  f32x4 acc[4][4] = {};

  auto stage1 = [&](int buf, int ks) {
    u16* d = sm1 + buf * 8192;
#pragma unroll
    for (int i = 0; i < 2; ++i) {
      gload16(a_src + (size_t)(i * 64) * C_ + ks * 32, d + (tid + i * 256) * 8);
      gload16(b_src + (size_t)(i * 64) * C_ + ks * 32, d + 4096 + (tid + i * 256) * 8);
    }
  };
  auto compute1 = [&](int buf) {
    const u16* A = sm1 + buf * 8192;
    const u16* Bt = A + 4096;
    s16x8 afr[4], bfr[4];
#pragma unroll
    for (int mf = 0; mf < 4; ++mf)
      afr[mf] = *reinterpret_cast<const s16x8*>(&A[(wm * 64 + mf * 16 + l15) * 32 + g4 * 8]);
#pragma unroll
    for (int nf = 0; nf < 4; ++nf)
      bfr[nf] = *reinterpret_cast<const s16x8*>(&Bt[(wn * 64 + nf * 16 + l15) * 32 + g4 * 8]);
#pragma unroll
    for (int mf = 0; mf < 4; ++mf)
#pragma unroll
      for (int nf = 0; nf < 4; ++nf)
        acc[mf][nf] = mfma16(afr[mf], bfr[nf], acc[mf][nf]);
  };

  stage1(0, 0); stage1(1, 1);
  int cur = 0;
#pragma unroll 1
  for (int ks = 0; ks < 15; ++ks) {
    asm volatile("s_waitcnt vmcnt(4)" ::: "memory");
    __builtin_amdgcn_s_barrier();
    compute1(cur);
    if (ks < 14) { int nb = cur + 2; if (nb >= 3) nb -= 3; stage1(nb, ks + 2); }
    cur = (cur == 2) ? 0 : cur + 1;
  }
  asm volatile("s_waitcnt vmcnt(0)" ::: "memory");
  __builtin_amdgcn_s_barrier();
  compute1(cur);          // ks = 15
  __syncthreads();        // all waves done reading bufs before lds_t overlay

  const float* bias = (p == 0) ? bg : (p == 1) ? bt : bp;
  const int cib = (mt & 1) * 128;
#pragma unroll
  for (int mf = 0; mf < 4; ++mf)
#pragma unroll
    for (int r = 0; r < 4; ++r) {
      float bv = bias[cib + wm * 64 + mf * 16 + g4 * 4 + r];
#pragma unroll
      for (int nf = 0; nf < 4; ++nf) acc[mf][nf][r] += bv;
    }

  if (p == 0) {
    // g: channel-major store via LDS transpose.  lds_t [128][136] u16
    u16* lds_t = sm1;
#pragma unroll
    for (int mf = 0; mf < 4; ++mf)
#pragma unroll
      for (int nf = 0; nf < 4; ++nf)
#pragma unroll
        for (int r = 0; r < 4; ++r)
          lds_t[(wm * 64 + mf * 16 + g4 * 4 + r) * 136 + wn * 64 + nf * 16 + l15] =
              f2bf(acc[mf][nf][r]);
    __syncthreads();
    const int m = tid >> 1, hh = tid & 1;
    size_t dst = ((size_t)b * CI_ + cib + m) * HW_ + n0g + hh * 64;
#pragma unroll
    for (int j = 0; j < 8; ++j)
      *reinterpret_cast<u16x8*>(&g_s[dst + j * 8]) =
          *reinterpret_cast<const u16x8*>(&lds_t[m * 136 + hh * 64 + j * 8]);
  } else {
    u16* outp = (p == 1) ? thetaT : phiT;
#pragma unroll
    for (int mf = 0; mf < 4; ++mf)
#pragma unroll
      for (int nf = 0; nf < 4; ++nf) {
        u16x4 h;
#pragma unroll
        for (int r = 0; r < 4; ++r) h[r] = f2bf(acc[mf][nf][r]);
        int n = n0g + wn * 64 + nf * 16 + l15;
        *reinterpret_cast<u16x4*>(
            &outp[((size_t)b * HW_ + n) * CI_ + cib + wm * 64 + mf * 16 + g4 * 4]) = h;
      }
  }
}

// ---------------------------------------------------------------------------
// K3: fused single-pass attention on 32x32x16 MFMA — the R11-verified best.
//  256 blocks x 512 thr (8 waves), n-tile 64, m-tile 128, 32 iterations.
//  LDS: PHI [128][256] 64KB + G [256][128] 64KB + P [64][128] 16KB + L.
//  All tiles XOR-swizzled at 16B-chunk x (row&15) -> ~conflict-free.
//  Conservative 2-sync skeleton:
//    A_it: { stage_g(it); qk(it) }   sync
//    B_it: { stage_phi(it+1); pv(it) } sync
// ---------------------------------------------------------------------------
#define OFF_PHI  0        // [128][256] u16 (65536 B)
#define OFF_G    32768    // [256][128] u16 (65536 B)
#define OFF_P    65536    // [64][128] u16 (16384 B)
#define OFF_LP   73728    // f32: Lp[8][32] + iL[64] -> total 148736 B

__global__ __launch_bounds__(512, 2) void k3_fused(
    const u16* __restrict__ thetaT, const u16* __restrict__ phiT,
    const u16* __restrict__ g_s, u16* __restrict__ y)
{
  extern __shared__ u16 smem[];
  float* Lp = (float*)(smem + OFF_LP);   // [8][32]
  float* iL = Lp + 256;                  // [64]

  const int tid = threadIdx.x;
  const int lane = tid & 63, w = tid >> 6;   // w in 0..7
  const int l31 = lane & 31, h = lane >> 5;  // h in 0..1
  const int l15 = lane & 15;

  const int bid = blockIdx.x;            // 256 = 8 xcd * 32
  const int xcd = bid & 7, slot = bid >> 3;
  const int b  = xcd >> 1;
  const int n0 = ((xcd & 1) * 32 + slot) * 64;   // 64 n-tiles of 64 per batch

  const int mh = w >> 1, nh = w & 1;    // QK roles
  const int cq = w >> 1, nh2 = w & 1;   // PV roles

  const u16* thb = thetaT + (size_t)b * HW_ * CI_;
  const u16* phb = phiT   + (size_t)b * HW_ * CI_;
  const u16* gsb = g_s    + (size_t)b * CI_ * HW_;

  // theta hoist: wave's 32 cols, 16 k-steps of 16 -> 64 VGPR (B operand)
  s16x8 thfr[16];
#pragma unroll
  for (int cs = 0; cs < 16; ++cs)
    thfr[cs] = *reinterpret_cast<const s16x8*>(
        &thb[(size_t)(n0 + nh * 32 + l31) * CI_ + cs * 16 + h * 8]);

  // staging maps (pre-swizzled global source, linear LDS dest = tid*16B)
  const int prow = tid >> 5, pj = tid & 31;   // phi: 16 rows/issue, 32 chunks
  const int grow = tid >> 4, gj = tid & 15;   // g: 32 rows/issue, 16 chunks
  const u16* ph_src = phb + (size_t)prow * CI_ + ((pj ^ prow) * 8);       // prow = m&15
  const u16* g_src  = gsb + (size_t)grow * HW_ + ((gj ^ (grow & 15)) * 8);
  const int ph_do = prow * 256 + pj * 8;
  const int g_do  = grow * 128 + gj * 8;

  auto stage_phi = [&](int mt) {
#pragma unroll
    for (int i = 0; i < 8; ++i)
      gload16(ph_src + (size_t)(mt + i * 16) * CI_, smem + OFF_PHI + ph_do + i * 4096);
  };
  auto stage_g = [&](int mt) {
#pragma unroll
    for (int i = 0; i < 8; ++i)
      gload16(g_src + mt + (size_t)(i * 32) * HW_, smem + OFF_G + g_do + i * 4096);
  };

  f32x16 oacc[2] = {};
  float psum = 0.f;

  auto qk_it = [&]() {
    const u16* phc = smem + OFF_PHI;
    u16* pb = smem + OFF_P;
    f32x16 acc = {};
    __builtin_amdgcn_s_setprio(1);
#pragma unroll
    for (int cs = 0; cs < 16; ++cs) {
      s16x8 a = *reinterpret_cast<const s16x8*>(
          &phc[(mh * 32 + l31) * 256 + (((cs * 2 + h) ^ l15) * 8)]);
      acc = mfma32(a, thfr[cs], acc);
    }
    __builtin_amdgcn_s_setprio(0);
    const int nloc = nh * 32 + l31;
#pragma unroll
    for (int g = 0; g < 4; ++g) {
      u16x4 pk;
#pragma unroll
      for (int r = 0; r < 4; ++r) {
        float e = __expf(acc[4 * g + r] * 0.0625f);
        psum += e;
        pk[r] = f2bf(e);
      }
      *reinterpret_cast<u16x4*>(
          &pb[nloc * 128 + (((mh * 4 + g) ^ l15) * 8) + h * 4]) = pk;
    }
  };
  auto pv_it = [&]() {
    const u16* pb = smem + OFF_P;
    const u16* gC = smem + OFF_G;
    const int nloc = nh2 * 32 + l31;
    __builtin_amdgcn_s_setprio(1);
#pragma unroll
    for (int ks = 0; ks < 8; ++ks) {
      s16x8 pa = *reinterpret_cast<const s16x8*>(
          &pb[nloc * 128 + (((ks * 2 + h) ^ l15) * 8)]);
#pragma unroll
      for (int ct = 0; ct < 2; ++ct) {
        int c = cq * 64 + ct * 32 + l31;
        s16x8 gb = *reinterpret_cast<const s16x8*>(
            &gC[c * 128 + (((ks * 2 + h) ^ l15) * 8)]);
        oacc[ct] = mfma32(pa, gb, oacc[ct]);
      }
    }
    __builtin_amdgcn_s_setprio(0);
  };

  // prologue: PHI <- phi(0)
  stage_phi(0);
  __syncthreads();

#pragma unroll 1
  for (int it = 0; it < 32; ++it) {
    stage_g(it * 128);                 // A: G <- g(it); qk reads PHI only
    qk_it();
    __syncthreads();                   // g staged + P written
    if (it < 31) stage_phi((it + 1) * 128);   // B: PHI <- phi(it+1); pv reads P,G
    pv_it();
    __syncthreads();                   // phi staged + P/G reads retired
  }

  // epilogue: L reduce -> iL; normalize + store y
  psum += __shfl_xor(psum, 32);
  if (lane < 32) Lp[w * 32 + lane] = psum;
  __syncthreads();
  if (tid < 64) {
    int nhh = tid >> 5, j = tid & 31;
    iL[tid] = 1.0f / (Lp[(0 * 2 + nhh) * 32 + j] + Lp[(1 * 2 + nhh) * 32 + j] +
                      Lp[(2 * 2 + nhh) * 32 + j] + Lp[(3 * 2 + nhh) * 32 + j]);
  }
  __syncthreads();

  u16* yb = y + ((size_t)b * HW_ + n0) * CI_;
#pragma unroll
  for (int ct = 0; ct < 2; ++ct) {
    int c = cq * 64 + ct * 32 + l31;
#pragma unroll
    for (int reg = 0; reg < 16; ++reg) {
      int nl = nh2 * 32 + (reg & 3) + 8 * (reg >> 2) + 4 * h;
      yb[(size_t)nl * CI_ + c] = f2bf(oacc[ct][reg] * iL[nl]);
    }
  }
}

// ---------------------------------------------------------------------------
// K4: z = W_w @ y^T + W_b, staged GEMM (M=512, N=16384, K=256).
//   Triple-buffered counted-vmcnt staging like K1.  (R5-proven; reverted
//   from R15's single-stage variant which lost ~10us to unhidden staging.)
// ---------------------------------------------------------------------------
__global__ __launch_bounds__(256) void k4_wconv(
    const u16* __restrict__ WwB, const u16* __restrict__ y, const float* __restrict__ Wb,
    u16* __restrict__ z, float* __restrict__ zsum, float* __restrict__ zsq)
{
  extern __shared__ u16 sm4[];
  __shared__ float lds_ps[2][128][2];
  const int tid = threadIdx.x;
  const int lane = tid & 63, wid = tid >> 6;
  const int wm = wid >> 1, wn = wid & 1;
  const int l15 = lane & 15, g4 = lane >> 4;

  const int bid = blockIdx.x;            // 512 = 8 xcd * 64
  const int xcd = bid & 7, slot = bid >> 3;
  const int b = xcd >> 1, half = xcd & 1;
  const int mt = slot & 3;
  const int nt = half * 16 + (slot >> 2);
  const int o0 = mt * 128, n0g = nt * 128;

  const int srow = tid >> 2, sch = tid & 3;
  const u16* a_src = WwB + (size_t)(o0 + srow) * CI_ + sch * 8;
  const u16* b_src = y + ((size_t)(b * HW_ + n0g + srow)) * CI_ + sch * 8;

  f32x4 acc[4][4] = {};

  auto stage4 = [&](int buf, int ks) {
    u16* d = sm4 + buf * 8192;
#pragma unroll
    for (int i = 0; i < 2; ++i) {
      gload16(a_src + (size_t)(i * 64) * CI_ + ks * 32, d + (tid + i * 256) * 8);
      gload16(b_src + (size_t)(i * 64) * CI_ + ks * 32, d + 4096 + (tid + i * 256) * 8);
    }
  };
  auto compute4 = [&](int buf) {
    const u16* A = sm4 + buf * 8192;
    const u16* Bt = A + 4096;
    s16x8 afr[4], bfr[4];
#pragma unroll
    for (int mf = 0; mf < 4; ++mf)
      afr[mf] = *reinterpret_cast<const s16x8*>(&A[(wm * 64 + mf * 16 + l15) * 32 + g4 * 8]);
#pragma unroll
    for (int nf = 0; nf < 4; ++nf)
      bfr[nf] = *reinterpret_cast<const s16x8*>(&Bt[(wn * 64 + nf * 16 + l15) * 32 + g4 * 8]);
#pragma unroll
    for (int mf = 0; mf < 4; ++mf)
#pragma unroll
      for (int nf = 0; nf < 4; ++nf)
        acc[mf][nf] = mfma16(afr[mf], bfr[nf], acc[mf][nf]);
  };

  stage4(0, 0); stage4(1, 1);
  int cur = 0;
#pragma unroll 1
  for (int ks = 0; ks < 7; ++ks) {
    asm volatile("s_waitcnt vmcnt(4)" ::: "memory");
    __builtin_amdgcn_s_barrier();
    compute4(cur);
    if (ks < 6) { int nb = cur + 2; if (nb >= 3) nb -= 3; stage4(nb, ks + 2); }
    cur = (cur == 2) ? 0 : cur + 1;
  }
  asm volatile("s_waitcnt vmcnt(0)" ::: "memory");
  __builtin_amdgcn_s_barrier();
  compute4(cur);          // ks = 7
  __syncthreads();

  // bias + BN partials + bf16 transpose store
  u16* lds_t = sm4;
#pragma unroll
  for (int mf = 0; mf < 4; ++mf)
#pragma unroll
    for (int r = 0; r < 4; ++r) {
      const int ol = wm * 64 + mf * 16 + g4 * 4 + r;
      float wb = Wb[o0 + ol];
      float s = 0.f, q = 0.f;
#pragma unroll
      for (int nf = 0; nf < 4; ++nf) {
        float zv = acc[mf][nf][r] + wb;
        s += zv; q += zv * zv;
        lds_t[ol * 136 + wn * 64 + nf * 16 + l15] = f2bf(zv);
      }
      s += __shfl_xor(s, 1); s += __shfl_xor(s, 2); s += __shfl_xor(s, 4); s += __shfl_xor(s, 8);
      q += __shfl_xor(q, 1); q += __shfl_xor(q, 2); q += __shfl_xor(q, 4); q += __shfl_xor(q, 8);
      if (l15 == 0) { lds_ps[wn][ol][0] = s; lds_ps[wn][ol][1] = q; }
    }
  __syncthreads();
  {
    const int m = tid >> 1, hh = tid & 1;
    size_t dst = ((size_t)(b * C_ + o0 + m)) * HW_ + n0g + hh * 64;
#pragma unroll
    for (int j = 0; j < 8; ++j)
      *reinterpret_cast<u16x8*>(&z[dst + j * 8]) =
          *reinterpret_cast<const u16x8*>(&lds_t[m * 136 + hh * 64 + j * 8]);
  }
  if (tid < 128) {
    int col = b * 32 + nt;
    zsum[(size_t)(o0 + tid) * 128 + col] = lds_ps[0][tid][0] + lds_ps[1][tid][0];
    zsq [(size_t)(o0 + tid) * 128 + col] = lds_ps[0][tid][1] + lds_ps[1][tid][1];
  }
}

// ---------------------------------------------------------------------------
// K5: BN stats finalize
// ---------------------------------------------------------------------------
__global__ void k5_bnstat(const float* __restrict__ zsum, const float* __restrict__ zsq,
                          const float* __restrict__ gamma, const float* __restrict__ beta,
                          float* __restrict__ bns, float* __restrict__ bnb)
{
  int ch = blockIdx.x * 256 + threadIdx.x;
  if (ch >= C_) return;
  float s = 0.f, q = 0.f;
  for (int i = 0; i < 128; ++i) { s += zsum[(size_t)ch * 128 + i]; q += zsq[(size_t)ch * 128 + i]; }
  const float inv_n = 1.0f / (B_ * HW_);
  float mean = s * inv_n;
  float var  = q * inv_n - mean * mean;
  float sc = gamma[ch] * rsqrtf(var + 1e-5f);
  bns[ch] = sc;
  bnb[ch] = beta[ch] - mean * sc;
}

// ---------------------------------------------------------------------------
// K6: out = z_bf16*scale[ch] + shift[ch] + x   (8 elems/thread, 4096 blocks)
// ---------------------------------------------------------------------------
__global__ __launch_bounds__(256) void k6_final(
    const u16* __restrict__ z, const float* __restrict__ x,
    const float* __restrict__ bns, const float* __restrict__ bnb,
    float* __restrict__ out)
{
  size_t i = ((size_t)blockIdx.x * 256 + threadIdx.x) * 8;
  int ch = (int)((i >> 12) & 511);
  float sc = bns[ch], sh = bnb[ch];
  u16x8 zv = *reinterpret_cast<const u16x8*>(&z[i]);
  float4 x0 = *reinterpret_cast<const float4*>(&x[i]);
  float4 x1 = *reinterpret_cast<const float4*>(&x[i + 4]);
  float4 o0, o1;
  o0.x = bf2f(zv[0]) * sc + sh + x0.x;
  o0.y = bf2f(zv[1]) * sc + sh + x0.y;
  o0.z = bf2f(zv[2]) * sc + sh + x0.z;
  o0.w = bf2f(zv[3]) * sc + sh + x0.w;
  o1.x = bf2f(zv[4]) * sc + sh + x1.x;
  o1.y = bf2f(zv[5]) * sc + sh + x1.y;
  o1.z = bf2f(zv[6]) * sc + sh + x1.z;
  o1.w = bf2f(zv[7]) * sc + sh + x1.w;
  *reinterpret_cast<float4*>(&out[i])     = o0;
  *reinterpret_cast<float4*>(&out[i + 4]) = o1;
}

// ---------------------------------------------------------------------------
// Workspace layout (peak 33.6 MB):
//   [0,8M):   xT half-buffer (k0x->k1), then y (k3->k4)
//   [8M,16M): thetaT (k1->k3), then zbf low half (k4->k6)
//   [16M,24M):phiT  (k1->k3), then zbf high half
//   [24M,32M):g_s   (k1->k3), then zsum/zsq/bns/bnb (k4->k6)
//   [32M,~33.6M): wB, WwB
// ---------------------------------------------------------------------------
extern "C" void kernel_launch(void* const* d_in, const int* in_sizes, int n_in,
                              void* d_out, int out_size, void* d_ws, size_t ws_size,
                              hipStream_t stream)
{
  (void)in_sizes; (void)n_in; (void)out_size; (void)ws_size;
  const float* x    = (const float*)d_in[0];
  const float* g_w  = (const float*)d_in[1];
  const float* g_b  = (const float*)d_in[2];
  const float* t_w  = (const float*)d_in[3];
  const float* t_b  = (const float*)d_in[4];
  const float* p_w  = (const float*)d_in[5];
  const float* p_b  = (const float*)d_in[6];
  const float* W_w  = (const float*)d_in[7];
  const float* W_b  = (const float*)d_in[8];
  const float* bng  = (const float*)d_in[9];
  const float* bnb_ = (const float*)d_in[10];

  char* ws = (char*)d_ws;
  const size_t M8 = (size_t)8 << 20;
  u16*   xT     = (u16*)(ws + 0);          // 8 MB (per-half)
  u16*   y      = (u16*)(ws + 0);          // overlays xT after k1
  u16*   thetaT = (u16*)(ws + M8);         // 8 MB
  u16*   phiT   = (u16*)(ws + 2 * M8);     // 8 MB
  u16*   g_s    = (u16*)(ws + 3 * M8);     // 8 MB
  u16*   zbf    = (u16*)(ws + M8);         // 16 MB, overlays theta+phi after k3
  float* zsum   = (float*)(ws + 3 * M8);   // overlays g_s after k3
  float* zsq    = (float*)(ws + 3 * M8 + 262144);
  float* bnsV   = (float*)(ws + 3 * M8 + 524288);
  float* bnbV   = (float*)(ws + 3 * M8 + 526336);
  u16*   wB     = (u16*)(ws + 4 * M8);     // 768 KB
  u16*   WwB    = (u16*)(ws + 4 * M8 + 786432);  // 256 KB
  float* out    = (float*)d_out;

  const int k1_lds = 49152;
  const int k3_lds = 148736;
  const int k4_lds = 49152;
  hipFuncSetAttribute(reinterpret_cast<const void*>(k1_proj),
                      hipFuncAttributeMaxDynamicSharedMemorySize, k1_lds);
  hipFuncSetAttribute(reinterpret_cast<const void*>(k3_fused),
                      hipFuncAttributeMaxDynamicSharedMemorySize, k3_lds);
  hipFuncSetAttribute(reinterpret_cast<const void*>(k4_wconv),
                      hipFuncAttributeMaxDynamicSharedMemorySize, k4_lds);

  hipLaunchKernelGGL(k0_wcvt, dim3(256), dim3(256), 0, stream,
                     g_w, t_w, p_w, W_w, wB, WwB);
  for (int half = 0; half < 2; ++half) {
    hipLaunchKernelGGL(k0_xt, dim3(64, 8, 2), dim3(256), 0, stream, x, xT, half * 2);
    hipLaunchKernelGGL(k1_proj, dim3(384), dim3(256), k1_lds, stream,
                       wB, xT, g_b, t_b, p_b, g_s, thetaT, phiT, half);
  }
  hipLaunchKernelGGL(k3_fused, dim3(256), dim3(512), k3_lds, stream,
                     thetaT, phiT, g_s, y);
  hipLaunchKernelGGL(k4_wconv, dim3(512), dim3(256), k4_lds, stream,
                     WwB, y, W_b, zbf, zsum, zsq);
  hipLaunchKernelGGL(k5_bnstat, dim3(2), dim3(256), 0, stream,
                     zsum, zsq, bng, bnb_, bnsV, bnbV);
  hipLaunchKernelGGL(k6_final, dim3(4096), dim3(256), 0, stream,
                     zbf, x, bnsV, bnbV, out);
}

// Round 17
// 179.683 us; speedup vs baseline: 1.6862x; 1.0419x over previous
//
#include <hip/hip_runtime.h>

typedef unsigned short u16;
typedef __attribute__((ext_vector_type(4))) u16 u16x4;
typedef __attribute__((ext_vector_type(8))) u16 u16x8;
typedef __attribute__((ext_vector_type(8))) short s16x8;   // 8 x bf16 (4 VGPRs)
typedef __attribute__((ext_vector_type(4))) float f32x4;
typedef __attribute__((ext_vector_type(16))) float f32x16;

#define B_  4
#define C_  512
#define CI_ 256
#define HW_ 4096

static __device__ __forceinline__ u16 f2bf(float f) {
  unsigned u = __float_as_uint(f);
  return (u16)((u + 0x7FFFu + ((u >> 16) & 1u)) >> 16);   // RNE
}
static __device__ __forceinline__ float bf2f(u16 h) {
  return __uint_as_float(((unsigned)h) << 16);
}

static __device__ __forceinline__ f32x4 mfma16(s16x8 a, s16x8 b, f32x4 c) {
  return __builtin_amdgcn_mfma_f32_16x16x32_bf16(a, b, c, 0, 0, 0);
}
static __device__ __forceinline__ f32x16 mfma32(s16x8 a, s16x8 b, f32x16 c) {
  return __builtin_amdgcn_mfma_f32_32x32x16_bf16(a, b, c, 0, 0, 0);
}

typedef __attribute__((address_space(3))) unsigned int as3_u32;
typedef const __attribute__((address_space(1))) unsigned int as1_u32;
static __device__ __forceinline__ void gload16(const u16* g, u16* l) {
  __builtin_amdgcn_global_load_lds((as1_u32*)g, (as3_u32*)l, 16, 0, 0);
}

// ---------------------------------------------------------------------------
// K0w: convert weights to bf16.  wB[768][512] = {g_w, theta_w, phi_w};
//      WwB[512][256] = W_w.
// ---------------------------------------------------------------------------
__global__ __launch_bounds__(256) void k0_wcvt(
    const float* __restrict__ wg, const float* __restrict__ wt,
    const float* __restrict__ wp, const float* __restrict__ Ww,
    u16* __restrict__ wB, u16* __restrict__ WwB)
{
  int idx = (blockIdx.x * 256 + threadIdx.x) * 8;   // over 524288 elems
  const float* src;
  u16* dst;
  if (idx < 393216) {
    int r = idx >> 17;                 // 0..2 region of 131072
    src = (r == 0 ? wg : r == 1 ? wt : wp) + (idx & 131071);
    dst = wB + idx;
  } else {
    src = Ww + (idx - 393216);
    dst = WwB + (idx - 393216);
  }
  float4 v0 = *reinterpret_cast<const float4*>(src);
  float4 v1 = *reinterpret_cast<const float4*>(src + 4);
  u16x8 h;
  h[0] = f2bf(v0.x); h[1] = f2bf(v0.y); h[2] = f2bf(v0.z); h[3] = f2bf(v0.w);
  h[4] = f2bf(v1.x); h[5] = f2bf(v1.y); h[6] = f2bf(v1.z); h[7] = f2bf(v1.w);
  *reinterpret_cast<u16x8*>(dst) = h;
}

// ---------------------------------------------------------------------------
// K0x: x (b0+z) (C,HW) f32 -> xT (z,HW,C) bf16 token-major; 64x64 LDS tiles.
// ---------------------------------------------------------------------------
__global__ __launch_bounds__(256) void k0_xt(
    const float* __restrict__ x, u16* __restrict__ xT, int b0)
{
  __shared__ u16 lds[64][72];   // [c][n]
  const int tid = threadIdx.x;
  const int n0 = blockIdx.x * 64, c0 = blockIdx.y * 64;
  const int bl = blockIdx.z;            // 0..1 local
  const int b = b0 + bl;
  const int nc = (tid & 15) * 4;
#pragma unroll
  for (int i = 0; i < 4; ++i) {
    int cr = (tid >> 4) + i * 16;
    float4 v = *reinterpret_cast<const float4*>(
        &x[((size_t)(b * C_ + c0 + cr)) * HW_ + n0 + nc]);
    u16x4 h; h[0] = f2bf(v.x); h[1] = f2bf(v.y); h[2] = f2bf(v.z); h[3] = f2bf(v.w);
    *reinterpret_cast<u16x4*>(&lds[cr][nc]) = h;
  }
  __syncthreads();
  const int n = tid & 63, cg = tid >> 6;
  u16x8 o0, o1;
#pragma unroll
  for (int j = 0; j < 8; ++j) { o0[j] = lds[cg * 16 + j][n]; o1[j] = lds[cg * 16 + 8 + j][n]; }
  size_t dstb = ((size_t)bl * HW_ + n0 + n) * C_ + c0 + cg * 16;
  *reinterpret_cast<u16x8*>(&xT[dstb])     = o0;
  *reinterpret_cast<u16x8*>(&xT[dstb + 8]) = o1;
}

// ---------------------------------------------------------------------------
// K1: fused projections as one staged NT GEMM (per 2-batch half).
//   tile 128x128, BK=32, triple-buffered counted-vmcnt staging.  (R5-proven)
// ---------------------------------------------------------------------------
__global__ __launch_bounds__(256) void k1_proj(
    const u16* __restrict__ wB, const u16* __restrict__ xT,
    const float* __restrict__ bg, const float* __restrict__ bt, const float* __restrict__ bp,
    u16* __restrict__ g_s, u16* __restrict__ thetaT, u16* __restrict__ phiT, int half)
{
  extern __shared__ u16 sm1[];   // 3 bufs of 8192 u16: A@+0 (4096), B@+4096
  const int tid = threadIdx.x;
  const int lane = tid & 63, wid = tid >> 6;
  const int wm = wid >> 1, wn = wid & 1;
  const int l15 = lane & 15, g4 = lane >> 4;

  const int bid = blockIdx.x;            // 384 = 12 * 32
  const int r12 = bid % 12;
  const int nt = bid / 12;               // 0..31
  const int mt = r12 >> 1;               // 0..5 (p = mt>>1)
  const int bl = r12 & 1;                // local batch
  const int b = half * 2 + bl;
  const int m0 = mt * 128, n0g = nt * 128;
  const int p = mt >> 1;

  const u16* xb = xT + (size_t)bl * HW_ * C_;

  const int srow = tid >> 2, sch = tid & 3;
  const u16* a_src = wB + (size_t)(m0 + srow) * C_ + sch * 8;
  const u16* b_src = xb + (size_t)(n0g + srow) * C_ + sch * 8;

  f32x4 acc[4][4] = {};

  auto stage1 = [&](int buf, int ks) {
    u16* d = sm1 + buf * 8192;
#pragma unroll
    for (int i = 0; i < 2; ++i) {
      gload16(a_src + (size_t)(i * 64) * C_ + ks * 32, d + (tid + i * 256) * 8);
      gload16(b_src + (size_t)(i * 64) * C_ + ks * 32, d + 4096 + (tid + i * 256) * 8);
    }
  };
  auto compute1 = [&](int buf) {
    const u16* A = sm1 + buf * 8192;
    const u16* Bt = A + 4096;
    s16x8 afr[4], bfr[4];
#pragma unroll
    for (int mf = 0; mf < 4; ++mf)
      afr[mf] = *reinterpret_cast<const s16x8*>(&A[(wm * 64 + mf * 16 + l15) * 32 + g4 * 8]);
#pragma unroll
    for (int nf = 0; nf < 4; ++nf)
      bfr[nf] = *reinterpret_cast<const s16x8*>(&Bt[(wn * 64 + nf * 16 + l15) * 32 + g4 * 8]);
#pragma unroll
    for (int mf = 0; mf < 4; ++mf)
#pragma unroll
      for (int nf = 0; nf < 4; ++nf)
        acc[mf][nf] = mfma16(afr[mf], bfr[nf], acc[mf][nf]);
  };

  stage1(0, 0); stage1(1, 1);
  int cur = 0;
#pragma unroll 1
  for (int ks = 0; ks < 15; ++ks) {
    asm volatile("s_waitcnt vmcnt(4)" ::: "memory");
    __builtin_amdgcn_s_barrier();
    compute1(cur);
    if (ks < 14) { int nb = cur + 2; if (nb >= 3) nb -= 3; stage1(nb, ks + 2); }
    cur = (cur == 2) ? 0 : cur + 1;
  }
  asm volatile("s_waitcnt vmcnt(0)" ::: "memory");
  __builtin_amdgcn_s_barrier();
  compute1(cur);          // ks = 15
  __syncthreads();        // all waves done reading bufs before lds_t overlay

  const float* bias = (p == 0) ? bg : (p == 1) ? bt : bp;
  const int cib = (mt & 1) * 128;
#pragma unroll
  for (int mf = 0; mf < 4; ++mf)
#pragma unroll
    for (int r = 0; r < 4; ++r) {
      float bv = bias[cib + wm * 64 + mf * 16 + g4 * 4 + r];
#pragma unroll
      for (int nf = 0; nf < 4; ++nf) acc[mf][nf][r] += bv;
    }

  if (p == 0) {
    // g: channel-major store via LDS transpose.  lds_t [128][136] u16
    u16* lds_t = sm1;
#pragma unroll
    for (int mf = 0; mf < 4; ++mf)
#pragma unroll
      for (int nf = 0; nf < 4; ++nf)
#pragma unroll
        for (int r = 0; r < 4; ++r)
          lds_t[(wm * 64 + mf * 16 + g4 * 4 + r) * 136 + wn * 64 + nf * 16 + l15] =
              f2bf(acc[mf][nf][r]);
    __syncthreads();
    const int m = tid >> 1, hh = tid & 1;
    size_t dst = ((size_t)b * CI_ + cib + m) * HW_ + n0g + hh * 64;
#pragma unroll
    for (int j = 0; j < 8; ++j)
      *reinterpret_cast<u16x8*>(&g_s[dst + j * 8]) =
          *reinterpret_cast<const u16x8*>(&lds_t[m * 136 + hh * 64 + j * 8]);
  } else {
    u16* outp = (p == 1) ? thetaT : phiT;
#pragma unroll
    for (int mf = 0; mf < 4; ++mf)
#pragma unroll
      for (int nf = 0; nf < 4; ++nf) {
        u16x4 h;
#pragma unroll
        for (int r = 0; r < 4; ++r) h[r] = f2bf(acc[mf][nf][r]);
        int n = n0g + wn * 64 + nf * 16 + l15;
        *reinterpret_cast<u16x4*>(
            &outp[((size_t)b * HW_ + n) * CI_ + cib + wm * 64 + mf * 16 + g4 * 4]) = h;
      }
  }
}

// ---------------------------------------------------------------------------
// K3: fused single-pass attention on 32x32x16 MFMA — the R11/R16-verified best.
//  256 blocks x 512 thr (8 waves), n-tile 64, m-tile 128, 32 iterations.
//  LDS: PHI [128][256] 64KB + G [256][128] 64KB + P [64][128] 16KB + L.
//  All tiles XOR-swizzled at 16B-chunk x (row&15) -> ~conflict-free.
//  Conservative 2-sync skeleton:
//    A_it: { stage_g(it); qk(it) }   sync
//    B_it: { stage_phi(it+1); pv(it) } sync
// ---------------------------------------------------------------------------
#define OFF_PHI  0        // [128][256] u16 (65536 B)
#define OFF_G    32768    // [256][128] u16 (65536 B)
#define OFF_P    65536    // [64][128] u16 (16384 B)
#define OFF_LP   73728    // f32: Lp[8][32] + iL[64] -> total 148736 B

__global__ __launch_bounds__(512, 2) void k3_fused(
    const u16* __restrict__ thetaT, const u16* __restrict__ phiT,
    const u16* __restrict__ g_s, u16* __restrict__ y)
{
  extern __shared__ u16 smem[];
  float* Lp = (float*)(smem + OFF_LP);   // [8][32]
  float* iL = Lp + 256;                  // [64]

  const int tid = threadIdx.x;
  const int lane = tid & 63, w = tid >> 6;   // w in 0..7
  const int l31 = lane & 31, h = lane >> 5;  // h in 0..1
  const int l15 = lane & 15;

  const int bid = blockIdx.x;            // 256 = 8 xcd * 32
  const int xcd = bid & 7, slot = bid >> 3;
  const int b  = xcd >> 1;
  const int n0 = ((xcd & 1) * 32 + slot) * 64;   // 64 n-tiles of 64 per batch

  const int mh = w >> 1, nh = w & 1;    // QK roles
  const int cq = w >> 1, nh2 = w & 1;   // PV roles

  const u16* thb = thetaT + (size_t)b * HW_ * CI_;
  const u16* phb = phiT   + (size_t)b * HW_ * CI_;
  const u16* gsb = g_s    + (size_t)b * CI_ * HW_;

  // theta hoist: wave's 32 cols, 16 k-steps of 16 -> 64 VGPR (B operand)
  s16x8 thfr[16];
#pragma unroll
  for (int cs = 0; cs < 16; ++cs)
    thfr[cs] = *reinterpret_cast<const s16x8*>(
        &thb[(size_t)(n0 + nh * 32 + l31) * CI_ + cs * 16 + h * 8]);

  // staging maps (pre-swizzled global source, linear LDS dest = tid*16B)
  const int prow = tid >> 5, pj = tid & 31;   // phi: 16 rows/issue, 32 chunks
  const int grow = tid >> 4, gj = tid & 15;   // g: 32 rows/issue, 16 chunks
  const u16* ph_src = phb + (size_t)prow * CI_ + ((pj ^ prow) * 8);       // prow = m&15
  const u16* g_src  = gsb + (size_t)grow * HW_ + ((gj ^ (grow & 15)) * 8);
  const int ph_do = prow * 256 + pj * 8;
  const int g_do  = grow * 128 + gj * 8;

  auto stage_phi = [&](int mt) {
#pragma unroll
    for (int i = 0; i < 8; ++i)
      gload16(ph_src + (size_t)(mt + i * 16) * CI_, smem + OFF_PHI + ph_do + i * 4096);
  };
  auto stage_g = [&](int mt) {
#pragma unroll
    for (int i = 0; i < 8; ++i)
      gload16(g_src + mt + (size_t)(i * 32) * HW_, smem + OFF_G + g_do + i * 4096);
  };

  f32x16 oacc[2] = {};
  float psum = 0.f;

  auto qk_it = [&]() {
    const u16* phc = smem + OFF_PHI;
    u16* pb = smem + OFF_P;
    f32x16 acc = {};
    __builtin_amdgcn_s_setprio(1);
#pragma unroll
    for (int cs = 0; cs < 16; ++cs) {
      s16x8 a = *reinterpret_cast<const s16x8*>(
          &phc[(mh * 32 + l31) * 256 + (((cs * 2 + h) ^ l15) * 8)]);
      acc = mfma32(a, thfr[cs], acc);
    }
    __builtin_amdgcn_s_setprio(0);
    const int nloc = nh * 32 + l31;
#pragma unroll
    for (int g = 0; g < 4; ++g) {
      u16x4 pk;
#pragma unroll
      for (int r = 0; r < 4; ++r) {
        float e = __expf(acc[4 * g + r] * 0.0625f);
        psum += e;
        pk[r] = f2bf(e);
      }
      *reinterpret_cast<u16x4*>(
          &pb[nloc * 128 + (((mh * 4 + g) ^ l15) * 8) + h * 4]) = pk;
    }
  };
  auto pv_it = [&]() {
    const u16* pb = smem + OFF_P;
    const u16* gC = smem + OFF_G;
    const int nloc = nh2 * 32 + l31;
    __builtin_amdgcn_s_setprio(1);
#pragma unroll
    for (int ks = 0; ks < 8; ++ks) {
      s16x8 pa = *reinterpret_cast<const s16x8*>(
          &pb[nloc * 128 + (((ks * 2 + h) ^ l15) * 8)]);
#pragma unroll
      for (int ct = 0; ct < 2; ++ct) {
        int c = cq * 64 + ct * 32 + l31;
        s16x8 gb = *reinterpret_cast<const s16x8*>(
            &gC[c * 128 + (((ks * 2 + h) ^ l15) * 8)]);
        oacc[ct] = mfma32(pa, gb, oacc[ct]);
      }
    }
    __builtin_amdgcn_s_setprio(0);
  };

  // prologue: PHI <- phi(0)
  stage_phi(0);
  __syncthreads();

#pragma unroll 1
  for (int it = 0; it < 32; ++it) {
    stage_g(it * 128);                 // A: G <- g(it); qk reads PHI only
    qk_it();
    __syncthreads();                   // g staged + P written
    if (it < 31) stage_phi((it + 1) * 128);   // B: PHI <- phi(it+1); pv reads P,G
    pv_it();
    __syncthreads();                   // phi staged + P/G reads retired
  }

  // epilogue: L reduce -> iL; normalize + store y
  psum += __shfl_xor(psum, 32);
  if (lane < 32) Lp[w * 32 + lane] = psum;
  __syncthreads();
  if (tid < 64) {
    int nhh = tid >> 5, j = tid & 31;
    iL[tid] = 1.0f / (Lp[(0 * 2 + nhh) * 32 + j] + Lp[(1 * 2 + nhh) * 32 + j] +
                      Lp[(2 * 2 + nhh) * 32 + j] + Lp[(3 * 2 + nhh) * 32 + j]);
  }
  __syncthreads();

  u16* yb = y + ((size_t)b * HW_ + n0) * CI_;
#pragma unroll
  for (int ct = 0; ct < 2; ++ct) {
    int c = cq * 64 + ct * 32 + l31;
#pragma unroll
    for (int reg = 0; reg < 16; ++reg) {
      int nl = nh2 * 32 + (reg & 3) + 8 * (reg >> 2) + 4 * h;
      yb[(size_t)nl * CI_ + c] = f2bf(oacc[ct][reg] * iL[nl]);
    }
  }
}

// ---------------------------------------------------------------------------
// K4: z = W_w @ y^T + W_b, staged GEMM (M=512, N=16384, K=256).
//   Triple-buffered counted-vmcnt staging like K1.  (R5-proven)
// ---------------------------------------------------------------------------
__global__ __launch_bounds__(256) void k4_wconv(
    const u16* __restrict__ WwB, const u16* __restrict__ y, const float* __restrict__ Wb,
    u16* __restrict__ z, float* __restrict__ zsum, float* __restrict__ zsq)
{
  extern __shared__ u16 sm4[];
  __shared__ float lds_ps[2][128][2];
  const int tid = threadIdx.x;
  const int lane = tid & 63, wid = tid >> 6;
  const int wm = wid >> 1, wn = wid & 1;
  const int l15 = lane & 15, g4 = lane >> 4;

  const int bid = blockIdx.x;            // 512 = 8 xcd * 64
  const int xcd = bid & 7, slot = bid >> 3;
  const int b = xcd >> 1, half = xcd & 1;
  const int mt = slot & 3;
  const int nt = half * 16 + (slot >> 2);
  const int o0 = mt * 128, n0g = nt * 128;

  const int srow = tid >> 2, sch = tid & 3;
  const u16* a_src = WwB + (size_t)(o0 + srow) * CI_ + sch * 8;
  const u16* b_src = y + ((size_t)(b * HW_ + n0g + srow)) * CI_ + sch * 8;

  f32x4 acc[4][4] = {};

  auto stage4 = [&](int buf, int ks) {
    u16* d = sm4 + buf * 8192;
#pragma unroll
    for (int i = 0; i < 2; ++i) {
      gload16(a_src + (size_t)(i * 64) * CI_ + ks * 32, d + (tid + i * 256) * 8);
      gload16(b_src + (size_t)(i * 64) * CI_ + ks * 32, d + 4096 + (tid + i * 256) * 8);
    }
  };
  auto compute4 = [&](int buf) {
    const u16* A = sm4 + buf * 8192;
    const u16* Bt = A + 4096;
    s16x8 afr[4], bfr[4];
#pragma unroll
    for (int mf = 0; mf < 4; ++mf)
      afr[mf] = *reinterpret_cast<const s16x8*>(&A[(wm * 64 + mf * 16 + l15) * 32 + g4 * 8]);
#pragma unroll
    for (int nf = 0; nf < 4; ++nf)
      bfr[nf] = *reinterpret_cast<const s16x8*>(&Bt[(wn * 64 + nf * 16 + l15) * 32 + g4 * 8]);
#pragma unroll
    for (int mf = 0; mf < 4; ++mf)
#pragma unroll
      for (int nf = 0; nf < 4; ++nf)
        acc[mf][nf] = mfma16(afr[mf], bfr[nf], acc[mf][nf]);
  };

  stage4(0, 0); stage4(1, 1);
  int cur = 0;
#pragma unroll 1
  for (int ks = 0; ks < 7; ++ks) {
    asm volatile("s_waitcnt vmcnt(4)" ::: "memory");
    __builtin_amdgcn_s_barrier();
    compute4(cur);
    if (ks < 6) { int nb = cur + 2; if (nb >= 3) nb -= 3; stage4(nb, ks + 2); }
    cur = (cur == 2) ? 0 : cur + 1;
  }
  asm volatile("s_waitcnt vmcnt(0)" ::: "memory");
  __builtin_amdgcn_s_barrier();
  compute4(cur);          // ks = 7
  __syncthreads();

  // bias + BN partials + bf16 transpose store
  u16* lds_t = sm4;
#pragma unroll
  for (int mf = 0; mf < 4; ++mf)
#pragma unroll
    for (int r = 0; r < 4; ++r) {
      const int ol = wm * 64 + mf * 16 + g4 * 4 + r;
      float wb = Wb[o0 + ol];
      float s = 0.f, q = 0.f;
#pragma unroll
      for (int nf = 0; nf < 4; ++nf) {
        float zv = acc[mf][nf][r] + wb;
        s += zv; q += zv * zv;
        lds_t[ol * 136 + wn * 64 + nf * 16 + l15] = f2bf(zv);
      }
      s += __shfl_xor(s, 1); s += __shfl_xor(s, 2); s += __shfl_xor(s, 4); s += __shfl_xor(s, 8);
      q += __shfl_xor(q, 1); q += __shfl_xor(q, 2); q += __shfl_xor(q, 4); q += __shfl_xor(q, 8);
      if (l15 == 0) { lds_ps[wn][ol][0] = s; lds_ps[wn][ol][1] = q; }
    }
  __syncthreads();
  {
    const int m = tid >> 1, hh = tid & 1;
    size_t dst = ((size_t)(b * C_ + o0 + m)) * HW_ + n0g + hh * 64;
#pragma unroll
    for (int j = 0; j < 8; ++j)
      *reinterpret_cast<u16x8*>(&z[dst + j * 8]) =
          *reinterpret_cast<const u16x8*>(&lds_t[m * 136 + hh * 64 + j * 8]);
  }
  if (tid < 128) {
    int col = b * 32 + nt;
    zsum[(size_t)(o0 + tid) * 128 + col] = lds_ps[0][tid][0] + lds_ps[1][tid][0];
    zsq [(size_t)(o0 + tid) * 128 + col] = lds_ps[0][tid][1] + lds_ps[1][tid][1];
  }
}

// ---------------------------------------------------------------------------
// K5: BN stats finalize — one wave per channel (was serial 128-iter loops).
//  128 blocks x 256 thr: wave w handles channel blockIdx.x*4 + w.
// ---------------------------------------------------------------------------
__global__ __launch_bounds__(256) void k5_bnstat(
    const float* __restrict__ zsum, const float* __restrict__ zsq,
    const float* __restrict__ gamma, const float* __restrict__ beta,
    float* __restrict__ bns, float* __restrict__ bnb)
{
  const int ch = blockIdx.x * 4 + (threadIdx.x >> 6);
  const int lane = threadIdx.x & 63;
  float s = zsum[(size_t)ch * 128 + lane] + zsum[(size_t)ch * 128 + 64 + lane];
  float q = zsq [(size_t)ch * 128 + lane] + zsq [(size_t)ch * 128 + 64 + lane];
  s += __shfl_xor(s, 1); s += __shfl_xor(s, 2); s += __shfl_xor(s, 4);
  s += __shfl_xor(s, 8); s += __shfl_xor(s, 16); s += __shfl_xor(s, 32);
  q += __shfl_xor(q, 1); q += __shfl_xor(q, 2); q += __shfl_xor(q, 4);
  q += __shfl_xor(q, 8); q += __shfl_xor(q, 16); q += __shfl_xor(q, 32);
  if (lane == 0) {
    const float inv_n = 1.0f / (B_ * HW_);
    float mean = s * inv_n;
    float var  = q * inv_n - mean * mean;
    float sc = gamma[ch] * rsqrtf(var + 1e-5f);
    bns[ch] = sc;
    bnb[ch] = beta[ch] - mean * sc;
  }
}

// ---------------------------------------------------------------------------
// K6: out = z_bf16*scale[ch] + shift[ch] + x   (8 elems/thread, 4096 blocks)
// ---------------------------------------------------------------------------
__global__ __launch_bounds__(256) void k6_final(
    const u16* __restrict__ z, const float* __restrict__ x,
    const float* __restrict__ bns, const float* __restrict__ bnb,
    float* __restrict__ out)
{
  size_t i = ((size_t)blockIdx.x * 256 + threadIdx.x) * 8;
  int ch = (int)((i >> 12) & 511);
  float sc = bns[ch], sh = bnb[ch];
  u16x8 zv = *reinterpret_cast<const u16x8*>(&z[i]);
  float4 x0 = *reinterpret_cast<const float4*>(&x[i]);
  float4 x1 = *reinterpret_cast<const float4*>(&x[i + 4]);
  float4 o0, o1;
  o0.x = bf2f(zv[0]) * sc + sh + x0.x;
  o0.y = bf2f(zv[1]) * sc + sh + x0.y;
  o0.z = bf2f(zv[2]) * sc + sh + x0.z;
  o0.w = bf2f(zv[3]) * sc + sh + x0.w;
  o1.x = bf2f(zv[4]) * sc + sh + x1.x;
  o1.y = bf2f(zv[5]) * sc + sh + x1.y;
  o1.z = bf2f(zv[6]) * sc + sh + x1.z;
  o1.w = bf2f(zv[7]) * sc + sh + x1.w;
  *reinterpret_cast<float4*>(&out[i])     = o0;
  *reinterpret_cast<float4*>(&out[i + 4]) = o1;
}

// ---------------------------------------------------------------------------
// Workspace layout (peak 33.6 MB):
//   [0,8M):   xT half-buffer (k0x->k1), then y (k3->k4)
//   [8M,16M): thetaT (k1->k3), then zbf low half (k4->k6)
//   [16M,24M):phiT  (k1->k3), then zbf high half
//   [24M,32M):g_s   (k1->k3), then zsum/zsq/bns/bnb (k4->k6)
//   [32M,~33.6M): wB, WwB
// ---------------------------------------------------------------------------
extern "C" void kernel_launch(void* const* d_in, const int* in_sizes, int n_in,
                              void* d_out, int out_size, void* d_ws, size_t ws_size,
                              hipStream_t stream)
{
  (void)in_sizes; (void)n_in; (void)out_size; (void)ws_size;
  const float* x    = (const float*)d_in[0];
  const float* g_w  = (const float*)d_in[1];
  const float* g_b  = (const float*)d_in[2];
  const float* t_w  = (const float*)d_in[3];
  const float* t_b  = (const float*)d_in[4];
  const float* p_w  = (const float*)d_in[5];
  const float* p_b  = (const float*)d_in[6];
  const float* W_w  = (const float*)d_in[7];
  const float* W_b  = (const float*)d_in[8];
  const float* bng  = (const float*)d_in[9];
  const float* bnb_ = (const float*)d_in[10];

  char* ws = (char*)d_ws;
  const size_t M8 = (size_t)8 << 20;
  u16*   xT     = (u16*)(ws + 0);          // 8 MB (per-half)
  u16*   y      = (u16*)(ws + 0);          // overlays xT after k1
  u16*   thetaT = (u16*)(ws + M8);         // 8 MB
  u16*   phiT   = (u16*)(ws + 2 * M8);     // 8 MB
  u16*   g_s    = (u16*)(ws + 3 * M8);     // 8 MB
  u16*   zbf    = (u16*)(ws + M8);         // 16 MB, overlays theta+phi after k3
  float* zsum   = (float*)(ws + 3 * M8);   // overlays g_s after k3
  float* zsq    = (float*)(ws + 3 * M8 + 262144);
  float* bnsV   = (float*)(ws + 3 * M8 + 524288);
  float* bnbV   = (float*)(ws + 3 * M8 + 526336);
  u16*   wB     = (u16*)(ws + 4 * M8);     // 768 KB
  u16*   WwB    = (u16*)(ws + 4 * M8 + 786432);  // 256 KB
  float* out    = (float*)d_out;

  const int k1_lds = 49152;
  const int k3_lds = 148736;
  const int k4_lds = 49152;
  hipFuncSetAttribute(reinterpret_cast<const void*>(k1_proj),
                      hipFuncAttributeMaxDynamicSharedMemorySize, k1_lds);
  hipFuncSetAttribute(reinterpret_cast<const void*>(k3_fused),
                      hipFuncAttributeMaxDynamicSharedMemorySize, k3_lds);
  hipFuncSetAttribute(reinterpret_cast<const void*>(k4_wconv),
                      hipFuncAttributeMaxDynamicSharedMemorySize, k4_lds);

  hipLaunchKernelGGL(k0_wcvt, dim3(256), dim3(256), 0, stream,
                     g_w, t_w, p_w, W_w, wB, WwB);
  for (int half = 0; half < 2; ++half) {
    hipLaunchKernelGGL(k0_xt, dim3(64, 8, 2), dim3(256), 0, stream, x, xT, half * 2);
    hipLaunchKernelGGL(k1_proj, dim3(384), dim3(256), k1_lds, stream,
                       wB, xT, g_b, t_b, p_b, g_s, thetaT, phiT, half);
  }
  hipLaunchKernelGGL(k3_fused, dim3(256), dim3(512), k3_lds, stream,
                     thetaT, phiT, g_s, y);
  hipLaunchKernelGGL(k4_wconv, dim3(512), dim3(256), k4_lds, stream,
                     WwB, y, W_b, zbf, zsum, zsq);
  hipLaunchKernelGGL(k5_bnstat, dim3(128), dim3(256), 0, stream,
                     zsum, zsq, bng, bnb_, bnsV, bnbV);
  hipLaunchKernelGGL(k6_final, dim3(4096), dim3(256), 0, stream,
                     zbf, x, bnsV, bnbV, out);
}